// Round 2
// baseline (2800.611 us; speedup 1.0000x reference)
//
#include <hip/hip_runtime.h>

// Deformable bottleneck block, MI355X/gfx950.
// All convs = implicit GEMM via mfma_f32_16x16x32_bf16 with 2-way bf16 split
// (hi/lo) for fp32-grade accuracy. Activations in NHWC; 3x3 convs use
// zero-padded [B][66][66][C] buffers and a 9-tap outer loop. Weights
// pre-packed to the exact LDS tile image (contiguous global_load_lds 16B).
// B-staging pre-swizzles the GLOBAL address (XOR on k-chunk) so k-major LDS
// fragment reads are <=2-way bank-conflicted (rule #21: both-sides-or-neither).
// Workspace: 227,868,672 B via era-aliasing (prior 429 MB exceeded ws_size ->
// silent no-op -> all-zero output, err == max|ref| = 2.2969).

typedef unsigned short u16;
typedef __bf16 bf16x8 __attribute__((ext_vector_type(8)));
typedef float f32x4 __attribute__((ext_vector_type(4)));
typedef _Float16 f16;

__device__ __forceinline__ u16 f2bf(float f) {
  unsigned u = __float_as_uint(f);
  u += 0x7fffu + ((u >> 16) & 1u);
  return (u16)(u >> 16);
}
__device__ __forceinline__ float bf2f(u16 h) { return __uint_as_float((unsigned)h << 16); }
__device__ __forceinline__ u16 f2h(float f) { f16 h = (f16)f; return __builtin_bit_cast(u16, h); }
__device__ __forceinline__ float h2f(u16 u) { return (float)__builtin_bit_cast(f16, u); }

// global -> LDS direct copy, 16B/lane. LDS dest wave-uniform base; global src per-lane.
__device__ __forceinline__ void gload16(const u16* g, u16* l) {
  __builtin_amdgcn_global_load_lds((__attribute__((address_space(1))) unsigned int*)g,
                                   (__attribute__((address_space(3))) unsigned int*)l,
                                   16, 0, 0);
}

__global__ __launch_bounds__(256) void zero_k(uint4* __restrict__ p, unsigned n) {
  unsigned i = blockIdx.x * 256u + threadIdx.x;
  const unsigned st = gridDim.x * 256u;
  uint4 z; z.x = 0u; z.y = 0u; z.z = 0u; z.w = 0u;
  for (; i < n; i += st) p[i] = z;
}

// Split fp32 weights (OIHW) into hi/lo bf16, packed as the LDS tile image:
// [M/128][K/32][kg(0..3)][m(0..127)][8], K linearized tap-major: k = tap*C + c.
__global__ __launch_bounds__(256) void pack_w(const float* __restrict__ w,
                                              u16* __restrict__ hi, u16* __restrict__ lo,
                                              int M, int C, int T) {
  const int AK = C * T;
  const int id = blockIdx.x * 256 + threadIdx.x;
  if (id >= M * AK) return;
  const int j = id & 7;
  const int slot = (id >> 3) & 511;
  const int rest = id >> 12;            // = mt*steps + step (512 slots * 8 = 4096)
  const int steps = AK >> 5;
  const int step = rest % steps;
  const int mt = rest / steps;
  const int kg = slot >> 7, m = slot & 127;
  const int k = step * 32 + kg * 8 + j; // tap-major K index
  const int tap = k / C;
  const int c = k - tap * C;
  const int mg = mt * 128 + m;
  const float v = w[((size_t)mg * C + c) * T + tap];
  const u16 h = f2bf(v);
  hi[id] = h;
  lo[id] = f2bf(v - bf2f(h));
}

// x NCHW fp32 -> padded hi/lo bf16 [4][66][66][1024] (interior only; border pre-zeroed)
__global__ __launch_bounds__(256) void prep_x(const float* __restrict__ x,
                                              u16* __restrict__ xphi, u16* __restrict__ xplo) {
  __shared__ float t[64][65];
  const int c0 = blockIdx.x * 64;
  const int y = blockIdx.y;
  const int b = blockIdx.z;
  const int tid = threadIdx.x;
#pragma unroll
  for (int i = 0; i < 16; ++i) {
    const int idx = i * 256 + tid;
    const int ci = idx >> 6, xi = idx & 63;
    t[ci][xi] = x[(((size_t)b * 1024 + c0 + ci) * 64 + y) * 64 + xi];
  }
  __syncthreads();
#pragma unroll
  for (int i = 0; i < 16; ++i) {
    const int idx = i * 256 + tid;
    const int xi = idx >> 6, ci = idx & 63;
    const float v = t[ci][xi];
    const u16 h = f2bf(v);
    const size_t pp = ((size_t)((b * 66 + y + 1) * 66 + (xi + 1))) * 1024 + c0 + ci;
    xphi[pp] = h;
    xplo[pp] = f2bf(v - bf2f(h));
  }
}

// Per-channel-offset bilinear resample. Source: PADDED hi/lo bf16 [4][66][66][C]
// (val = hi + lo, fp32-grade). off: fp16 NHWC [pix][2C] (2c+0 -> dy, 2c+1 -> dx).
// Dest: hi/lo bf16, padded ([4][66][66][C]) if PADDST else [pix][C].
template <int C, int PADDST>
__global__ __launch_bounds__(256) void deform_k(const u16* __restrict__ shi,
                                                const u16* __restrict__ slo,
                                                const u16* __restrict__ off,
                                                u16* __restrict__ dhi, u16* __restrict__ dlo) {
  const int id = blockIdx.x * 256 + threadIdx.x;
  const int c = id & (C - 1);
  const int pix = id / C;
  const int b = pix >> 12;
  const int y = (pix >> 6) & 63;
  const int x = pix & 63;
  const unsigned ov = *(const unsigned*)(off + (size_t)pix * (2 * C) + 2 * c);
  const float py = fminf(fmaxf((float)y + h2f((u16)(ov & 0xffffu)), 0.f), 63.f);
  const float px = fminf(fmaxf((float)x + h2f((u16)(ov >> 16)), 0.f), 63.f);
  const int y0i = (int)py, x0i = (int)px;            // py,px >= 0 -> trunc == floor
  const int y1i = min(y0i + 1, 63), x1i = min(x0i + 1, 63);
  const float wy = py - (float)y0i, wx = px - (float)x0i;
  const int bb66 = b * 66;
  auto at = [&](int yi, int xi) -> size_t {
    return ((size_t)((bb66 + yi + 1) * 66 + (xi + 1))) * C + c;
  };
  const size_t a00 = at(y0i, x0i), a01 = at(y0i, x1i);
  const size_t a10 = at(y1i, x0i), a11 = at(y1i, x1i);
  const float v00 = bf2f(shi[a00]) + bf2f(slo[a00]);
  const float v01 = bf2f(shi[a01]) + bf2f(slo[a01]);
  const float v10 = bf2f(shi[a10]) + bf2f(slo[a10]);
  const float v11 = bf2f(shi[a11]) + bf2f(slo[a11]);
  const float val = v00 * (1.f - wy) * (1.f - wx) + v01 * (1.f - wy) * wx +
                    v10 * wy * (1.f - wx) + v11 * wy * wx;
  const u16 h = f2bf(val);
  const size_t d = PADDST ? at(y, x) : (size_t)id;
  dhi[d] = h;
  dlo[d] = f2bf(val - bf2f(h));
}

// Implicit-GEMM conv. 128x128 tile, 4 waves (2x2 of 64x64), BK=32; 3 MFMAs per
// fragment pair (hi*hi + lo*hi + hi*lo).
// EPI: 0 = +bias -> fp16 NHWC offsets (o16a)
//      1 = BN    -> padded hi/lo bf16 (o16a, o16b)
//      2 = BN+ReLU -> fp32 NCHW (outF = d_out)
template <int TAPS, int PAD, int EPI, int CC>
__global__ __launch_bounds__(256, 2) void gemm_conv(
    const u16* __restrict__ Aph, const u16* __restrict__ Apl,
    const u16* __restrict__ Bh, const u16* __restrict__ Bl,
    const float* __restrict__ p0, const float* __restrict__ p1,
    const float* __restrict__ p2, const float* __restrict__ p3,
    float* __restrict__ outF, u16* __restrict__ o16a, u16* __restrict__ o16b, int M) {
  __shared__ u16 lds[4 * 4096];  // [Ah|Al|Bh|Bl] x (512 slots x 8 u16) = 32 KiB
  constexpr int steps = TAPS * (CC / 32);
  const int tid = threadIdx.x;
  const int w = tid >> 6, lane = tid & 63;
  const int wm = (w >> 1) * 64, wn = (w & 1) * 64;
  const int kg = lane >> 4, lm = lane & 15;
  const int mt = blockIdx.x, nt = blockIdx.y;
  const int b_img = nt >> 5;          // n-tile = 2 image rows of one batch
  const int y0 = (nt & 31) * 2;

  f32x4 acc[4][4];
  const f32x4 fz = {0.f, 0.f, 0.f, 0.f};
#pragma unroll
  for (int i = 0; i < 4; ++i)
#pragma unroll
    for (int j = 0; j < 4; ++j) acc[i][j] = fz;

  const u16* Abase_h = Aph + (size_t)mt * steps * 4096;
  const u16* Abase_l = Apl + (size_t)mt * steps * 4096;

  for (int step = 0; step < steps; ++step) {
    const int tap = (TAPS == 1) ? 0 : (step / (CC / 32));
    const int c0 = (step - tap * (CC / 32)) * 32;
    const int ky = (TAPS == 9) ? (tap / 3) : 0;
    const int kx = (TAPS == 9) ? (tap % 3) : 0;

#pragma unroll
    for (int it = 0; it < 2; ++it) {
      const int slot = w * 128 + it * 64 + lane;
      const unsigned ldso = (unsigned)(w * 128 + it * 64) * 8u;  // wave-uniform
      // A: packed == LDS image, contiguous.
      const size_t ga = (size_t)step * 4096 + (size_t)slot * 8;
      gload16(Abase_h + ga, &lds[0 * 4096 + ldso]);
      gload16(Abase_l + ga, &lds[1 * 4096 + ldso]);
      // B: LDS layout [n(0..127)][kq(0..3)][8]; swizzle the SOURCE k-chunk so
      // the XOR on the read side lands on the right data.
      const int n = slot >> 2, kq = slot & 3;
      const int kga = kq ^ ((n >> 1) & 3);
      size_t gb;
      if (PAD) {
        const int r = n >> 6, xc = n & 63;
        gb = ((size_t)((b_img * 66 + (y0 + r + ky)) * 66 + (xc + kx))) * CC +
             (size_t)(c0 + kga * 8);
      } else {
        gb = (size_t)(nt * 128 + n) * CC + (size_t)(c0 + kga * 8);
      }
      gload16(Bh + gb, &lds[2 * 4096 + ldso]);
      gload16(Bl + gb, &lds[3 * 4096 + ldso]);
    }
    __syncthreads();  // drains vmcnt (global_load_lds) before use

    bf16x8 ah[4], al[4], bh[4], bl[4];
#pragma unroll
    for (int f = 0; f < 4; ++f) {
      // A fragment: row = lane&15, k-chunk = lane>>4; [kg][m][8] -> conflict-free.
      const unsigned ao = (unsigned)(kg * 128 + wm + f * 16 + lm) * 8u;
      ah[f] = *(const bf16x8*)&lds[0 * 4096 + ao];
      al[f] = *(const bf16x8*)&lds[1 * 4096 + ao];
      // B fragment: col = lane&15 group, k-chunk = lane>>4, XOR-deswizzled.
      const int n = wn + f * 16 + lm;
      const unsigned bo = (unsigned)(n * 4 + (kg ^ ((n >> 1) & 3))) * 8u;
      bh[f] = *(const bf16x8*)&lds[2 * 4096 + bo];
      bl[f] = *(const bf16x8*)&lds[3 * 4096 + bo];
    }
#pragma unroll
    for (int i = 0; i < 4; ++i)
#pragma unroll
      for (int j = 0; j < 4; ++j) {
        acc[i][j] = __builtin_amdgcn_mfma_f32_16x16x32_bf16(ah[i], bh[j], acc[i][j], 0, 0, 0);
        acc[i][j] = __builtin_amdgcn_mfma_f32_16x16x32_bf16(al[i], bh[j], acc[i][j], 0, 0, 0);
        acc[i][j] = __builtin_amdgcn_mfma_f32_16x16x32_bf16(ah[i], bl[j], acc[i][j], 0, 0, 0);
      }
    __syncthreads();
  }

  // Epilogue. C/D layout (m89-verified): col = lane&15, row = (lane>>4)*4 + reg.
  const int ocb = mt * 128 + wm + kg * 4;
#pragma unroll
  for (int fi = 0; fi < 4; ++fi) {
    const int oc0 = ocb + fi * 16;
    f32x4 scl, sft;
    if (EPI == 0) {
#pragma unroll
      for (int j = 0; j < 4; ++j) { scl[j] = 1.f; sft[j] = p0[oc0 + j]; }
    } else {
#pragma unroll
      for (int j = 0; j < 4; ++j) {
        const float inv = p0[oc0 + j] / sqrtf(p3[oc0 + j] + 1e-5f);
        scl[j] = inv;
        sft[j] = p1[oc0 + j] - p2[oc0 + j] * inv;
      }
    }
#pragma unroll
    for (int fj = 0; fj < 4; ++fj) {
      const int pix = nt * 128 + wn + fj * 16 + lm;
      f32x4 r = acc[fi][fj] * scl + sft;
      if (EPI == 0) {
        // fp16 offsets, NHWC [pix][M]
        uint2 hv;
        hv.x = (unsigned)f2h(r[0]) | ((unsigned)f2h(r[1]) << 16);
        hv.y = (unsigned)f2h(r[2]) | ((unsigned)f2h(r[3]) << 16);
        *(uint2*)(o16a + (size_t)pix * M + oc0) = hv;
      } else if (EPI == 1) {
        const int bb = pix >> 12, yy = (pix >> 6) & 63, xx = pix & 63;
        const size_t pp = ((size_t)((bb * 66 + yy + 1) * 66 + (xx + 1))) * M + oc0;
        const u16 h0 = f2bf(r[0]), h1 = f2bf(r[1]), h2 = f2bf(r[2]), h3 = f2bf(r[3]);
        uint2 hv; hv.x = (unsigned)h0 | ((unsigned)h1 << 16);
        hv.y = (unsigned)h2 | ((unsigned)h3 << 16);
        *(uint2*)(o16a + pp) = hv;
        const u16 l0 = f2bf(r[0] - bf2f(h0)), l1 = f2bf(r[1] - bf2f(h1));
        const u16 l2 = f2bf(r[2] - bf2f(h2)), l3 = f2bf(r[3] - bf2f(h3));
        uint2 lv; lv.x = (unsigned)l0 | ((unsigned)l1 << 16);
        lv.y = (unsigned)l2 | ((unsigned)l3 << 16);
        *(uint2*)(o16b + pp) = lv;
      } else {
        const int bb = pix >> 12, pin = pix & 4095;
#pragma unroll
        for (int j = 0; j < 4; ++j)
          outF[((size_t)(bb * M + oc0 + j)) * 4096 + pin] = fmaxf(r[j], 0.f);
      }
    }
  }
}

extern "C" void kernel_launch(void* const* d_in, const int* in_sizes, int n_in,
                              void* d_out, int out_size, void* d_ws, size_t ws_size,
                              hipStream_t stream) {
  (void)in_sizes; (void)out_size;
  if (n_in < 22) return;
  const float* x   = (const float*)d_in[0];
  const float* ow1 = (const float*)d_in[1];
  const float* ob1 = (const float*)d_in[2];
  const float* ow2 = (const float*)d_in[3];
  const float* ob2 = (const float*)d_in[4];
  const float* ow3 = (const float*)d_in[5];
  const float* ob3 = (const float*)d_in[6];
  const float* w1  = (const float*)d_in[7];
  const float* w2  = (const float*)d_in[8];
  const float* w3  = (const float*)d_in[9];
  const float* g1 = (const float*)d_in[10], *b1 = (const float*)d_in[11];
  const float* m1 = (const float*)d_in[12], *v1 = (const float*)d_in[13];
  const float* g2 = (const float*)d_in[14], *b2 = (const float*)d_in[15];
  const float* m2 = (const float*)d_in[16], *v2 = (const float*)d_in[17];
  const float* g3 = (const float*)d_in[18], *b3 = (const float*)d_in[19];
  const float* m3 = (const float*)d_in[20], *v3 = (const float*)d_in[21];

  char* W = (char*)d_ws;
  // ---- workspace map: 227,868,672 bytes, two aliased eras ----
  constexpr size_t P66_1024 = 4ull * 66 * 66 * 1024 * 2;  // 35,684,352 (one split half)
  constexpr size_t P66_256  = 4ull * 66 * 66 * 256 * 2;   //  8,921,088
  constexpr size_t SZ_OFF1  = 4ull * 4096 * 2048 * 2;     // 67,108,864 (fp16)
  constexpr size_t SZ_OFF2  = 4ull * 4096 * 512 * 2;      // 16,777,216 (fp16)
  constexpr size_t SZ_H1    = 4ull * 4096 * 1024 * 2;     // 33,554,432 (one half)
  constexpr size_t SZ_H3    = 4ull * 4096 * 256 * 2;      //  8,388,608 (one half)
  // Region A: era1 = padded x (hi|lo); era2 = h2p_hi|h2p_lo|t2p_hi|t2p_lo
  constexpr size_t A0 = 0;
  constexpr size_t o_xp1_hi = A0, o_xp1_lo = A0 + P66_1024;
  constexpr size_t o_h2p_hi = A0, o_h2p_lo = A0 + P66_256;
  constexpr size_t o_t2p_hi = A0 + 2 * P66_256, o_t2p_lo = A0 + 3 * P66_256;
  static_assert(4 * P66_256 == P66_1024, "era2 fills xp1_hi exactly");
  // Region B: era1 = off1 fp16; era2 = t1p_hi|t1p_lo, off2, off3; h3 aliases t1p
  constexpr size_t B0 = A0 + 2 * P66_1024;
  constexpr size_t o_off1   = B0;
  constexpr size_t o_t1p_hi = B0, o_t1p_lo = B0 + P66_256;
  constexpr size_t o_off2   = B0 + 2 * P66_256;
  constexpr size_t o_off3   = o_off2 + SZ_OFF2;
  constexpr size_t o_h3_hi  = B0, o_h3_lo = B0 + SZ_H3;   // after t1p dead (D2)
  static_assert(o_off3 + SZ_OFF2 <= B0 + SZ_OFF1, "era2 fits off1 slot");
  static_assert(2 * SZ_H3 <= 2 * P66_256, "h3 fits t1p slot");
  // Weights region; h1 aliases the ow1 slot (ow1 dead after G1).
  constexpr size_t WT0 = B0 + SZ_OFF1;
  constexpr size_t SZ_OW1 = 2048ull * 9216 * 2, SZ_W1 = 256ull * 1024 * 2;
  constexpr size_t SZ_OW2 = 512ull * 2304 * 2,  SZ_W2 = 256ull * 2304 * 2;
  constexpr size_t SZ_OW3 = 512ull * 2304 * 2,  SZ_W3 = 1024ull * 256 * 2;
  constexpr size_t o_ow1h = WT0,              o_ow1l = o_ow1h + SZ_OW1;
  constexpr size_t o_h1_hi = o_ow1h,          o_h1_lo = o_ow1l;  // SZ_H1 <= SZ_OW1
  static_assert(SZ_H1 <= SZ_OW1, "h1 fits ow1 slot");
  constexpr size_t o_w1h  = o_ow1l + SZ_OW1,  o_w1l  = o_w1h + SZ_W1;
  constexpr size_t o_ow2h = o_w1l + SZ_W1,    o_ow2l = o_ow2h + SZ_OW2;
  constexpr size_t o_w2h  = o_ow2l + SZ_OW2,  o_w2l  = o_w2h + SZ_W2;
  constexpr size_t o_ow3h = o_w2l + SZ_W2,    o_ow3l = o_ow3h + SZ_OW3;
  constexpr size_t o_w3h  = o_ow3l + SZ_OW3,  o_w3l  = o_w3h + SZ_W3;
  constexpr size_t WS_NEED = o_w3l + SZ_W3;   // 227,868,672
  if (ws_size < WS_NEED) return;  // cannot run without corrupting memory

  auto U = [&](size_t o) { return (u16*)(W + o); };
  auto zero = [&](size_t off, size_t bytes) {
    const unsigned n = (unsigned)(bytes / 16);
    unsigned grid = (n + 255) / 256; if (grid > 4096) grid = 4096;
    zero_k<<<grid, 256, 0, stream>>>((uint4*)(W + off), n);
  };
  auto pack = [&](const float* src, size_t oh, size_t ol, int M, int C, int T) {
    const int n = M * C * T;
    pack_w<<<(n + 255) / 256, 256, 0, stream>>>(src, U(oh), U(ol), M, C, T);
  };

  // ---- weight prep (re-done every call; ws is re-poisoned) ----
  pack(ow1, o_ow1h, o_ow1l, 2048, 1024, 9);
  pack(w1,  o_w1h,  o_w1l,  256, 1024, 1);
  pack(ow2, o_ow2h, o_ow2l, 512, 256, 9);
  pack(w2,  o_w2h,  o_w2l,  256, 256, 9);
  pack(ow3, o_ow3h, o_ow3l, 512, 256, 9);
  pack(w3,  o_w3h,  o_w3l,  1024, 256, 1);

  // ---- stage 0: pad+split x ----
  zero(o_xp1_hi, 2 * P66_1024);
  prep_x<<<dim3(16, 64, 4), 256, 0, stream>>>(x, U(o_xp1_hi), U(o_xp1_lo));

  // G1: offset-conv1 (3x3, 1024 -> 2048) -> off1 fp16
  gemm_conv<9, 1, 0, 1024><<<dim3(16, 128), 256, 0, stream>>>(
      U(o_ow1h), U(o_ow1l), U(o_xp1_hi), U(o_xp1_lo),
      ob1, nullptr, nullptr, nullptr, nullptr, U(o_off1), nullptr, 2048);
  // D1: deform(x, off1) -> h1 hi/lo (unpadded; conv1 is 1x1). Dest = ow1 slot (dead).
  deform_k<1024, 0><<<65536, 256, 0, stream>>>(
      U(o_xp1_hi), U(o_xp1_lo), U(o_off1), U(o_h1_hi), U(o_h1_lo));

  // era switch: xp1 dead (region A), off1 dead (region B head).
  zero(o_t1p_hi, 2 * P66_256);   // t1p borders
  zero(o_h2p_hi, 4 * P66_256);   // h2p + t2p borders
  // G2: conv1 1x1 + BN1 -> t1 padded hi/lo
  gemm_conv<1, 0, 1, 1024><<<dim3(2, 128), 256, 0, stream>>>(
      U(o_w1h), U(o_w1l), U(o_h1_hi), U(o_h1_lo),
      g1, b1, m1, v1, nullptr, U(o_t1p_hi), U(o_t1p_lo), 256);
  // G3: offset-conv2 (3x3, 256 -> 512) -> off2 fp16
  gemm_conv<9, 1, 0, 256><<<dim3(4, 128), 256, 0, stream>>>(
      U(o_ow2h), U(o_ow2l), U(o_t1p_hi), U(o_t1p_lo),
      ob2, nullptr, nullptr, nullptr, nullptr, U(o_off2), nullptr, 512);
  // D2: deform(t1, off2) -> h2 padded hi/lo (conv2 is 3x3)
  deform_k<256, 1><<<16384, 256, 0, stream>>>(
      U(o_t1p_hi), U(o_t1p_lo), U(o_off2), U(o_h2p_hi), U(o_h2p_lo));
  // G4: conv2 3x3 + BN2 -> t2 padded hi/lo
  gemm_conv<9, 1, 1, 256><<<dim3(2, 128), 256, 0, stream>>>(
      U(o_w2h), U(o_w2l), U(o_h2p_hi), U(o_h2p_lo),
      g2, b2, m2, v2, nullptr, U(o_t2p_hi), U(o_t2p_lo), 256);
  // G5: offset-conv3 -> off3 fp16
  gemm_conv<9, 1, 0, 256><<<dim3(4, 128), 256, 0, stream>>>(
      U(o_ow3h), U(o_ow3l), U(o_t2p_hi), U(o_t2p_lo),
      ob3, nullptr, nullptr, nullptr, nullptr, U(o_off3), nullptr, 512);
  // D3: deform(t2, off3) -> h3 hi/lo (unpadded; conv3 is 1x1). Dest = t1p slot (dead).
  deform_k<256, 0><<<16384, 256, 0, stream>>>(
      U(o_t2p_hi), U(o_t2p_lo), U(o_off3), U(o_h3_hi), U(o_h3_lo));
  // G6: conv3 1x1 + BN3 + ReLU -> d_out (NCHW fp32)
  gemm_conv<1, 0, 2, 256><<<dim3(8, 128), 256, 0, stream>>>(
      U(o_w3h), U(o_w3l), U(o_h3_hi), U(o_h3_lo),
      g3, b3, m3, v3, (float*)d_out, nullptr, nullptr, 1024);
}

// Round 3
// 1388.152 us; speedup vs baseline: 2.0175x; 2.0175x over previous
//
#include <hip/hip_runtime.h>

// Deformable bottleneck block, MI355X/gfx950.  Round 3.
// Precision plan: activations single bf16 everywhere; offset-conv weights
// single bf16 (1 MFMA/frag); main-path weights hi/lo split (2 MFMA/frag =
// exact-weight x bf16-activation). Offsets fp16. Predicted absmax ~1.6e-2
// vs threshold 4.6e-2.
// GEMM: implicit-GEMM, 128x128 tile, 4 waves, BK=32, global_load_lds(16B),
// B-source XOR pre-swizzle (read-side XOR matches), chunked XCD-bijective
// grid swizzle so each XCD L2 holds one A-tile (mt-major work chunks).

typedef unsigned short u16;
typedef __bf16 bf16x8 __attribute__((ext_vector_type(8)));
typedef float f32x4 __attribute__((ext_vector_type(4)));
typedef _Float16 f16;

__device__ __forceinline__ u16 f2bf(float f) {
  unsigned u = __float_as_uint(f);
  u += 0x7fffu + ((u >> 16) & 1u);
  return (u16)(u >> 16);
}
__device__ __forceinline__ float bf2f(u16 h) { return __uint_as_float((unsigned)h << 16); }
__device__ __forceinline__ u16 f2h(float f) { f16 h = (f16)f; return __builtin_bit_cast(u16, h); }
__device__ __forceinline__ float h2f(u16 u) { return (float)__builtin_bit_cast(f16, u); }

__device__ __forceinline__ void gload16(const u16* g, u16* l) {
  __builtin_amdgcn_global_load_lds((__attribute__((address_space(1))) unsigned int*)g,
                                   (__attribute__((address_space(3))) unsigned int*)l,
                                   16, 0, 0);
}

__global__ __launch_bounds__(256) void zero_k(uint4* __restrict__ p, unsigned n) {
  unsigned i = blockIdx.x * 256u + threadIdx.x;
  const unsigned st = gridDim.x * 256u;
  uint4 z; z.x = 0u; z.y = 0u; z.z = 0u; z.w = 0u;
  for (; i < n; i += st) p[i] = z;
}

// fp32 OIHW weights -> packed LDS tile image [M/128][K/32][kg][m][8],
// K tap-major (k = tap*C + c). SPLIT=1 also writes the bf16 lo residual.
template <int SPLIT>
__global__ __launch_bounds__(256) void pack_w(const float* __restrict__ w,
                                              u16* __restrict__ hi, u16* __restrict__ lo,
                                              int M, int C, int T) {
  const int AK = C * T;
  const int id = blockIdx.x * 256 + threadIdx.x;
  if (id >= M * AK) return;
  const int j = id & 7;
  const int slot = (id >> 3) & 511;
  const int rest = id >> 12;
  const int steps = AK >> 5;
  const int step = rest % steps;
  const int mt = rest / steps;
  const int kg = slot >> 7, m = slot & 127;
  const int k = step * 32 + kg * 8 + j;
  const int tap = k / C;
  const int c = k - tap * C;
  const int mg = mt * 128 + m;
  const float v = w[((size_t)mg * C + c) * T + tap];
  const u16 h = f2bf(v);
  hi[id] = h;
  if (SPLIT) lo[id] = f2bf(v - bf2f(h));
}

// x NCHW fp32 -> padded bf16 [4][66][66][1024] (interior; border pre-zeroed)
__global__ __launch_bounds__(256) void prep_x(const float* __restrict__ x,
                                              u16* __restrict__ xp) {
  __shared__ float t[64][65];
  const int c0 = blockIdx.x * 64;
  const int y = blockIdx.y;
  const int b = blockIdx.z;
  const int tid = threadIdx.x;
#pragma unroll
  for (int i = 0; i < 16; ++i) {
    const int idx = i * 256 + tid;
    const int ci = idx >> 6, xi = idx & 63;
    t[ci][xi] = x[(((size_t)b * 1024 + c0 + ci) * 64 + y) * 64 + xi];
  }
  __syncthreads();
#pragma unroll
  for (int i = 0; i < 16; ++i) {
    const int idx = i * 256 + tid;
    const int xi = idx >> 6, ci = idx & 63;
    xp[((size_t)((b * 66 + y + 1) * 66 + (xi + 1))) * 1024 + c0 + ci] = f2bf(t[ci][xi]);
  }
}

// Bilinear resample. src: PADDED bf16 [4][66][66][C]; off: fp16 [pix][2C]
// (2c -> dy, 2c+1 -> dx). Dest bf16: padded if PADDST else [pix][C].
template <int C, int PADDST>
__global__ __launch_bounds__(256) void deform_k(const u16* __restrict__ src,
                                                const u16* __restrict__ off,
                                                u16* __restrict__ dst) {
  const int id = blockIdx.x * 256 + threadIdx.x;
  const int c = id & (C - 1);
  const int pix = id / C;
  const int b = pix >> 12;
  const int y = (pix >> 6) & 63;
  const int x = pix & 63;
  const unsigned ov = *(const unsigned*)(off + (size_t)pix * (2 * C) + 2 * c);
  const float py = fminf(fmaxf((float)y + h2f((u16)(ov & 0xffffu)), 0.f), 63.f);
  const float px = fminf(fmaxf((float)x + h2f((u16)(ov >> 16)), 0.f), 63.f);
  const int y0i = (int)py, x0i = (int)px;
  const int y1i = min(y0i + 1, 63), x1i = min(x0i + 1, 63);
  const float wy = py - (float)y0i, wx = px - (float)x0i;
  const int bb66 = b * 66;
  auto at = [&](int yi, int xi) -> size_t {
    return ((size_t)((bb66 + yi + 1) * 66 + (xi + 1))) * C + c;
  };
  const float v00 = bf2f(src[at(y0i, x0i)]);
  const float v01 = bf2f(src[at(y0i, x1i)]);
  const float v10 = bf2f(src[at(y1i, x0i)]);
  const float v11 = bf2f(src[at(y1i, x1i)]);
  const float val = v00 * (1.f - wy) * (1.f - wx) + v01 * (1.f - wy) * wx +
                    v10 * wy * (1.f - wx) + v11 * wy * wx;
  const size_t d = PADDST ? at(y, x) : (size_t)id;
  dst[d] = f2bf(val);
}

// Implicit-GEMM conv. WSPLIT: 0 = single-bf16 weights (1 MFMA), 1 = hi/lo
// weights (2 MFMA). B (activations) always single bf16.
// EPI: 0 = +bias -> fp16 offsets; 1 = BN -> padded bf16; 2 = BN+ReLU -> fp32 NCHW.
template <int TAPS, int PAD, int EPI, int CC, int WSPLIT>
__global__ __launch_bounds__(256, 2) void gemm_conv(
    const u16* __restrict__ Aph, const u16* __restrict__ Apl,
    const u16* __restrict__ Bh,
    const float* __restrict__ p0, const float* __restrict__ p1,
    const float* __restrict__ p2, const float* __restrict__ p3,
    float* __restrict__ outF, u16* __restrict__ o16a, int M) {
  constexpr int NB = 2 + WSPLIT;           // Ah, (Al), Bh
  __shared__ u16 lds[NB * 4096];           // 16 or 24 KiB
  constexpr int steps = TAPS * (CC / 32);
  const int tid = threadIdx.x;
  const int w = tid >> 6, lane = tid & 63;
  const int wm = (w >> 1) * 64, wn = (w & 1) * 64;
  const int kg = lane >> 4, lm = lane & 15;
  // chunked XCD-bijective swizzle: XCD k gets a contiguous mt-major chunk.
  const int wg = blockIdx.x;
  const int chunk = (int)(gridDim.x >> 3);
  const int g = (wg & 7) * chunk + (wg >> 3);
  const int mt = g >> 7, nt = g & 127;     // NT = 128 always
  const int b_img = nt >> 5;
  const int y0 = (nt & 31) * 2;

  f32x4 acc[4][4];
  const f32x4 fz = {0.f, 0.f, 0.f, 0.f};
#pragma unroll
  for (int i = 0; i < 4; ++i)
#pragma unroll
    for (int j = 0; j < 4; ++j) acc[i][j] = fz;

  const u16* Abase_h = Aph + (size_t)mt * steps * 4096;
  const u16* Abase_l = WSPLIT ? (Apl + (size_t)mt * steps * 4096) : nullptr;

  for (int step = 0; step < steps; ++step) {
    const int tap = (TAPS == 1) ? 0 : (step / (CC / 32));
    const int c0 = (step - tap * (CC / 32)) * 32;
    const int ky = (TAPS == 9) ? (tap / 3) : 0;
    const int kx = (TAPS == 9) ? (tap % 3) : 0;

#pragma unroll
    for (int it = 0; it < 2; ++it) {
      const int slot = w * 128 + it * 64 + lane;
      const unsigned ldso = (unsigned)(w * 128 + it * 64) * 8u;  // wave-uniform
      const size_t ga = (size_t)step * 4096 + (size_t)slot * 8;
      gload16(Abase_h + ga, &lds[0 * 4096 + ldso]);
      if (WSPLIT) gload16(Abase_l + ga, &lds[1 * 4096 + ldso]);
      // B: LDS [n][kq][8]; pre-swizzle SOURCE k-chunk, XOR-matched on read.
      const int n = slot >> 2, kq = slot & 3;
      const int kga = kq ^ ((n >> 1) & 3);
      size_t gb;
      if (PAD) {
        const int r = n >> 6, xc = n & 63;
        gb = ((size_t)((b_img * 66 + (y0 + r + ky)) * 66 + (xc + kx))) * CC +
             (size_t)(c0 + kga * 8);
      } else {
        gb = (size_t)(nt * 128 + n) * CC + (size_t)(c0 + kga * 8);
      }
      gload16(Bh + gb, &lds[(NB - 1) * 4096 + ldso]);
    }
    __syncthreads();

    bf16x8 ah[4], al[4], bh[4];
#pragma unroll
    for (int f = 0; f < 4; ++f) {
      const unsigned ao = (unsigned)(kg * 128 + wm + f * 16 + lm) * 8u;
      ah[f] = *(const bf16x8*)&lds[0 * 4096 + ao];
      if (WSPLIT) al[f] = *(const bf16x8*)&lds[1 * 4096 + ao];
      const int n = wn + f * 16 + lm;
      const unsigned bo = (unsigned)(n * 4 + (kg ^ ((n >> 1) & 3))) * 8u;
      bh[f] = *(const bf16x8*)&lds[(NB - 1) * 4096 + bo];
    }
#pragma unroll
    for (int i = 0; i < 4; ++i)
#pragma unroll
      for (int j = 0; j < 4; ++j) {
        acc[i][j] = __builtin_amdgcn_mfma_f32_16x16x32_bf16(ah[i], bh[j], acc[i][j], 0, 0, 0);
        if (WSPLIT)
          acc[i][j] = __builtin_amdgcn_mfma_f32_16x16x32_bf16(al[i], bh[j], acc[i][j], 0, 0, 0);
      }
    __syncthreads();
  }

  // Epilogue. C/D layout: col = lane&15, row = (lane>>4)*4 + reg.
  const int ocb = mt * 128 + wm + kg * 4;
#pragma unroll
  for (int fi = 0; fi < 4; ++fi) {
    const int oc0 = ocb + fi * 16;
    f32x4 scl, sft;
    if (EPI == 0) {
#pragma unroll
      for (int j = 0; j < 4; ++j) { scl[j] = 1.f; sft[j] = p0[oc0 + j]; }
    } else {
#pragma unroll
      for (int j = 0; j < 4; ++j) {
        const float inv = p0[oc0 + j] / sqrtf(p3[oc0 + j] + 1e-5f);
        scl[j] = inv;
        sft[j] = p1[oc0 + j] - p2[oc0 + j] * inv;
      }
    }
#pragma unroll
    for (int fj = 0; fj < 4; ++fj) {
      const int pix = nt * 128 + wn + fj * 16 + lm;
      f32x4 r = acc[fi][fj] * scl + sft;
      if (EPI == 0) {
        uint2 hv;
        hv.x = (unsigned)f2h(r[0]) | ((unsigned)f2h(r[1]) << 16);
        hv.y = (unsigned)f2h(r[2]) | ((unsigned)f2h(r[3]) << 16);
        *(uint2*)(o16a + (size_t)pix * M + oc0) = hv;
      } else if (EPI == 1) {
        const int bb = pix >> 12, yy = (pix >> 6) & 63, xx = pix & 63;
        const size_t pp = ((size_t)((bb * 66 + yy + 1) * 66 + (xx + 1))) * M + oc0;
        uint2 hv;
        hv.x = (unsigned)f2bf(r[0]) | ((unsigned)f2bf(r[1]) << 16);
        hv.y = (unsigned)f2bf(r[2]) | ((unsigned)f2bf(r[3]) << 16);
        *(uint2*)(o16a + pp) = hv;
      } else {
        const int bb = pix >> 12, pin = pix & 4095;
#pragma unroll
        for (int j = 0; j < 4; ++j)
          outF[((size_t)(bb * M + oc0 + j)) * 4096 + pin] = fmaxf(r[j], 0.f);
      }
    }
  }
}

extern "C" void kernel_launch(void* const* d_in, const int* in_sizes, int n_in,
                              void* d_out, int out_size, void* d_ws, size_t ws_size,
                              hipStream_t stream) {
  (void)in_sizes; (void)out_size;
  if (n_in < 22) return;
  const float* x   = (const float*)d_in[0];
  const float* ow1 = (const float*)d_in[1];
  const float* ob1 = (const float*)d_in[2];
  const float* ow2 = (const float*)d_in[3];
  const float* ob2 = (const float*)d_in[4];
  const float* ow3 = (const float*)d_in[5];
  const float* ob3 = (const float*)d_in[6];
  const float* w1  = (const float*)d_in[7];
  const float* w2  = (const float*)d_in[8];
  const float* w3  = (const float*)d_in[9];
  const float* g1 = (const float*)d_in[10], *b1 = (const float*)d_in[11];
  const float* m1 = (const float*)d_in[12], *v1 = (const float*)d_in[13];
  const float* g2 = (const float*)d_in[14], *b2 = (const float*)d_in[15];
  const float* m2 = (const float*)d_in[16], *v2 = (const float*)d_in[17];
  const float* g3 = (const float*)d_in[18], *b3 = (const float*)d_in[19];
  const float* m3 = (const float*)d_in[20], *v3 = (const float*)d_in[21];

  char* W = (char*)d_ws;
  // ---- workspace map: 185,630,720 B (prior 227.9 MB passed -> safe) ----
  constexpr size_t P66_1024 = 4ull * 66 * 66 * 1024 * 2;  // 35,684,352
  constexpr size_t P66_256  = 4ull * 66 * 66 * 256 * 2;   //  8,921,088
  constexpr size_t SZ_OFF1  = 4ull * 4096 * 2048 * 2;     // 67,108,864
  constexpr size_t SZ_OFF2  = 4ull * 4096 * 512 * 2;      // 16,777,216
  constexpr size_t SZ_H1    = 4ull * 4096 * 1024 * 2;     // 33,554,432
  constexpr size_t SZ_H3    = 4ull * 4096 * 256 * 2;      //  8,388,608
  constexpr size_t SZ_OW1 = 2048ull * 9216 * 2;           // 37,748,736
  constexpr size_t SZ_W1  = 256ull * 1024 * 2;
  constexpr size_t SZ_OW2 = 512ull * 2304 * 2;
  constexpr size_t SZ_W2  = 256ull * 2304 * 2;
  constexpr size_t SZ_OW3 = 512ull * 2304 * 2;
  constexpr size_t SZ_W3  = 1024ull * 256 * 2;

  constexpr size_t o_ow1h = 0;
  constexpr size_t o_xp   = o_ow1h + SZ_OW1;              // 37,748,736
  constexpr size_t o_off1 = o_xp + P66_1024;              // 73,433,088
  // aliases inside the off1 slot (off1 dead after D1):
  constexpr size_t o_t1p  = o_off1;                       // 8,921,088
  constexpr size_t o_off2 = o_t1p + P66_256;              // 16,777,216
  constexpr size_t o_h2p  = o_off2 + SZ_OFF2;             // 8,921,088
  constexpr size_t o_t2p  = o_h2p + P66_256;              // 8,921,088
  static_assert(o_t2p + P66_256 <= o_off1 + SZ_OFF1, "era2 fits off1 slot");
  constexpr size_t o_h1   = o_off1 + SZ_OFF1;             // 140,541,952
  // aliases inside the h1 slot (h1 dead after G2):
  constexpr size_t o_off3 = o_h1;
  constexpr size_t o_h3   = o_off3 + SZ_OFF2;
  static_assert(o_h3 + SZ_H3 <= o_h1 + SZ_H1, "off3+h3 fit h1 slot");
  constexpr size_t o_w1h  = o_h1 + SZ_H1;
  constexpr size_t o_w1l  = o_w1h + SZ_W1;
  constexpr size_t o_ow2h = o_w1l + SZ_W1;
  constexpr size_t o_w2h  = o_ow2h + SZ_OW2;
  constexpr size_t o_w2l  = o_w2h + SZ_W2;
  constexpr size_t o_ow3h = o_w2l + SZ_W2;
  constexpr size_t o_w3h  = o_ow3h + SZ_OW3;
  constexpr size_t o_w3l  = o_w3h + SZ_W3;
  constexpr size_t WS_NEED = o_w3l + SZ_W3;               // 185,630,720
  if (ws_size < WS_NEED) return;

  auto U = [&](size_t o) { return (u16*)(W + o); };
  auto zero = [&](size_t off, size_t bytes) {
    const unsigned n = (unsigned)(bytes / 16);
    unsigned grid = (n + 255) / 256; if (grid > 4096) grid = 4096;
    zero_k<<<grid, 256, 0, stream>>>((uint4*)(W + off), n);
  };

  // ---- weight prep (re-done every call; ws is re-poisoned) ----
  {
    int n;
    n = 2048 * 9216; pack_w<0><<<(n + 255) / 256, 256, 0, stream>>>(ow1, U(o_ow1h), nullptr, 2048, 1024, 9);
    n = 256 * 1024;  pack_w<1><<<(n + 255) / 256, 256, 0, stream>>>(w1, U(o_w1h), U(o_w1l), 256, 1024, 1);
    n = 512 * 2304;  pack_w<0><<<(n + 255) / 256, 256, 0, stream>>>(ow2, U(o_ow2h), nullptr, 512, 256, 9);
    n = 256 * 2304;  pack_w<1><<<(n + 255) / 256, 256, 0, stream>>>(w2, U(o_w2h), U(o_w2l), 256, 256, 9);
    n = 512 * 2304;  pack_w<0><<<(n + 255) / 256, 256, 0, stream>>>(ow3, U(o_ow3h), nullptr, 512, 256, 9);
    n = 1024 * 256;  pack_w<1><<<(n + 255) / 256, 256, 0, stream>>>(w3, U(o_w3h), U(o_w3l), 1024, 256, 1);
  }

  // ---- stage 0: pad x -> bf16 ----
  zero(o_xp, P66_1024);
  prep_x<<<dim3(16, 64, 4), 256, 0, stream>>>(x, U(o_xp));

  // G1: offset-conv1 (3x3, 1024 -> 2048), single-bf16 -> off1 fp16
  gemm_conv<9, 1, 0, 1024, 0><<<2048, 256, 0, stream>>>(
      U(o_ow1h), nullptr, U(o_xp), ob1, nullptr, nullptr, nullptr,
      nullptr, U(o_off1), 2048);
  // D1: deform(x, off1) -> h1 (unpadded; conv1 is 1x1)
  deform_k<1024, 0><<<65536, 256, 0, stream>>>(U(o_xp), U(o_off1), U(o_h1));

  // era switch: off1 slot now hosts t1p/off2/h2p/t2p.
  zero(o_t1p, P66_256);
  zero(o_h2p, 2 * P66_256);     // h2p + t2p contiguous
  // G2: conv1 1x1 + BN1 (weights split) -> t1 padded bf16
  gemm_conv<1, 0, 1, 1024, 1><<<256, 256, 0, stream>>>(
      U(o_w1h), U(o_w1l), U(o_h1), g1, b1, m1, v1,
      nullptr, U(o_t1p), 256);
  // G3: offset-conv2 (3x3, 256 -> 512), single-bf16 -> off2 fp16
  gemm_conv<9, 1, 0, 256, 0><<<512, 256, 0, stream>>>(
      U(o_ow2h), nullptr, U(o_t1p), ob2, nullptr, nullptr, nullptr,
      nullptr, U(o_off2), 512);
  // D2: deform(t1, off2) -> h2 padded (conv2 is 3x3)
  deform_k<256, 1><<<16384, 256, 0, stream>>>(U(o_t1p), U(o_off2), U(o_h2p));
  // G4: conv2 3x3 + BN2 (weights split) -> t2 padded bf16
  gemm_conv<9, 1, 1, 256, 1><<<256, 256, 0, stream>>>(
      U(o_w2h), U(o_w2l), U(o_h2p), g2, b2, m2, v2,
      nullptr, U(o_t2p), 256);
  // G5: offset-conv3, single-bf16 -> off3 fp16 (h1 slot; h1 dead)
  gemm_conv<9, 1, 0, 256, 0><<<512, 256, 0, stream>>>(
      U(o_ow3h), nullptr, U(o_t2p), ob3, nullptr, nullptr, nullptr,
      nullptr, U(o_off3), 512);
  // D3: deform(t2, off3) -> h3 (unpadded; conv3 is 1x1)
  deform_k<256, 0><<<16384, 256, 0, stream>>>(U(o_t2p), U(o_off3), U(o_h3));
  // G6: conv3 1x1 + BN3 + ReLU (weights split) -> d_out (NCHW fp32)
  gemm_conv<1, 0, 2, 256, 1><<<1024, 256, 0, stream>>>(
      U(o_w3h), U(o_w3l), U(o_h3), g3, b3, m3, v3,
      (float*)d_out, nullptr, 1024);
}

// Round 4
// 1128.237 us; speedup vs baseline: 2.4823x; 1.2304x over previous
//
#include <hip/hip_runtime.h>

// Deformable bottleneck block, MI355X/gfx950.  Round 4.
// Offset convs (G1/G3/G5, 84% of FLOPs) on a 256^2-tile 8-phase counted-vmcnt
// kernel (T2 swizzle + T3/T4 + T5); main-path convs on the proven 128^2 kernel.

typedef unsigned short u16;
typedef __bf16 bf16x8 __attribute__((ext_vector_type(8)));
typedef float f32x4 __attribute__((ext_vector_type(4)));
typedef _Float16 f16;

__device__ __forceinline__ u16 f2bf(float f) {
  unsigned u = __float_as_uint(f);
  u += 0x7fffu + ((u >> 16) & 1u);
  return (u16)(u >> 16);
}
__device__ __forceinline__ float bf2f(u16 h) { return __uint_as_float((unsigned)h << 16); }
__device__ __forceinline__ u16 f2h(float f) { f16 h = (f16)f; return __builtin_bit_cast(u16, h); }
__device__ __forceinline__ float h2f(u16 u) { return (float)__builtin_bit_cast(f16, u); }

__device__ __forceinline__ void gload16(const u16* g, u16* l) {
  __builtin_amdgcn_global_load_lds((__attribute__((address_space(1))) unsigned int*)g,
                                   (__attribute__((address_space(3))) unsigned int*)l,
                                   16, 0, 0);
}

#define VM8() asm volatile("s_waitcnt vmcnt(8)" ::: "memory")
#define VM4() asm volatile("s_waitcnt vmcnt(4)" ::: "memory")
#define VM0() asm volatile("s_waitcnt vmcnt(0)" ::: "memory")
#define BAR()                                   \
  do {                                          \
    asm volatile("" ::: "memory");              \
    __builtin_amdgcn_s_barrier();               \
    asm volatile("" ::: "memory");              \
  } while (0)
#define LGK0()                                          \
  do {                                                  \
    asm volatile("s_waitcnt lgkmcnt(0)" ::: "memory");  \
    __builtin_amdgcn_sched_barrier(0);                  \
  } while (0)

__global__ __launch_bounds__(256) void zero_k(uint4* __restrict__ p, unsigned n) {
  unsigned i = blockIdx.x * 256u + threadIdx.x;
  const unsigned st = gridDim.x * 256u;
  uint4 z; z.x = 0u; z.y = 0u; z.z = 0u; z.w = 0u;
  for (; i < n; i += st) p[i] = z;
}

// ---- 128^2-kernel weight pack (unchanged layout) ----
template <int SPLIT>
__global__ __launch_bounds__(256) void pack_w(const float* __restrict__ w,
                                              u16* __restrict__ hi, u16* __restrict__ lo,
                                              int M, int C, int T) {
  const int AK = C * T;
  const int id = blockIdx.x * 256 + threadIdx.x;
  if (id >= M * AK) return;
  const int j = id & 7;
  const int slot = (id >> 3) & 511;
  const int rest = id >> 12;
  const int steps = AK >> 5;
  const int step = rest % steps;
  const int mt = rest / steps;
  const int kg = slot >> 7, m = slot & 127;
  const int k = step * 32 + kg * 8 + j;
  const int tap = k / C;
  const int c = k - tap * C;
  const int mg = mt * 128 + m;
  const float v = w[((size_t)mg * C + c) * T + tap];
  const u16 h = f2bf(v);
  hi[id] = h;
  if (SPLIT) lo[id] = f2bf(v - bf2f(h));
}

// ---- 256^2 8-phase kernel weight pack: [mt][half H][slot d][8], with the
// read-side XOR swizzle baked in: slot d holds W[row=d>>2][k = H*32 +
// ((d&3)^((row>>1)&3))*8 .. +8]  (K tap-major). ----
template <int CC, int T>
__global__ __launch_bounds__(256) void pack8_w(const float* __restrict__ w,
                                               u16* __restrict__ dst, int M) {
  constexpr int KT2 = 2 * (T * CC / 64);
  const int id = blockIdx.x * 256 + threadIdx.x;
  if (id >= M * CC * T) return;
  const int j = id & 7;
  const int d = (id >> 3) & 1023;
  const int rest = id >> 13;
  const int H = rest % KT2;
  const int mt = rest / KT2;
  const int row = d >> 2, kq = d & 3;
  const int k = H * 32 + ((kq ^ ((row >> 1) & 3)) * 8) + j;
  const int tap = k / CC, c = k - tap * CC;
  const int oc = mt * 256 + row;
  dst[id] = f2bf(w[((size_t)oc * CC + c) * T + tap]);
}

// x NCHW fp32 -> padded bf16 [4][66][66][1024]
__global__ __launch_bounds__(256) void prep_x(const float* __restrict__ x,
                                              u16* __restrict__ xp) {
  __shared__ float t[64][65];
  const int c0 = blockIdx.x * 64;
  const int y = blockIdx.y;
  const int b = blockIdx.z;
  const int tid = threadIdx.x;
#pragma unroll
  for (int i = 0; i < 16; ++i) {
    const int idx = i * 256 + tid;
    const int ci = idx >> 6, xi = idx & 63;
    t[ci][xi] = x[(((size_t)b * 1024 + c0 + ci) * 64 + y) * 64 + xi];
  }
  __syncthreads();
#pragma unroll
  for (int i = 0; i < 16; ++i) {
    const int idx = i * 256 + tid;
    const int xi = idx >> 6, ci = idx & 63;
    xp[((size_t)((b * 66 + y + 1) * 66 + (xi + 1))) * 1024 + c0 + ci] = f2bf(t[ci][xi]);
  }
}

// Bilinear resample (unchanged from round 3).
template <int C, int PADDST>
__global__ __launch_bounds__(256) void deform_k(const u16* __restrict__ src,
                                                const u16* __restrict__ off,
                                                u16* __restrict__ dst) {
  const int id = blockIdx.x * 256 + threadIdx.x;
  const int c = id & (C - 1);
  const int pix = id / C;
  const int b = pix >> 12;
  const int y = (pix >> 6) & 63;
  const int x = pix & 63;
  const unsigned ov = *(const unsigned*)(off + (size_t)pix * (2 * C) + 2 * c);
  const float py = fminf(fmaxf((float)y + h2f((u16)(ov & 0xffffu)), 0.f), 63.f);
  const float px = fminf(fmaxf((float)x + h2f((u16)(ov >> 16)), 0.f), 63.f);
  const int y0i = (int)py, x0i = (int)px;
  const int y1i = min(y0i + 1, 63), x1i = min(x0i + 1, 63);
  const float wy = py - (float)y0i, wx = px - (float)x0i;
  const int bb66 = b * 66;
  auto at = [&](int yi, int xi) -> size_t {
    return ((size_t)((bb66 + yi + 1) * 66 + (xi + 1))) * C + c;
  };
  const float v00 = bf2f(src[at(y0i, x0i)]);
  const float v01 = bf2f(src[at(y0i, x1i)]);
  const float v10 = bf2f(src[at(y1i, x0i)]);
  const float v11 = bf2f(src[at(y1i, x1i)]);
  const float val = v00 * (1.f - wy) * (1.f - wx) + v01 * (1.f - wy) * wx +
                    v10 * wy * (1.f - wx) + v11 * wy * wx;
  const size_t d = PADDST ? at(y, x) : (size_t)id;
  dst[d] = f2bf(val);
}

// ================= 256^2 8-phase offset-conv GEMM =================
// BM=BN=256, BK=64 (2 K-halves of 32), 512 thr = 8 waves (2M x 4N),
// per-wave 128x64 out. LDS 128 KiB = buf[2] x op[A,B] x kh[2] x 16 KiB.
// Per tile t (4 phases A..D): A: ld Bfrag(k0)+Afrag(m0-3,k0), stage A-half
// 2t+3; B: Afrag(m4-7,k0), stage B-half 2t+3, vmcnt(8); C/D same on k1,
// staging halves 2t+4, vmcnt(8). Each phase: barrier; lgkmcnt(0); 16 MFMA
// in setprio(1); barrier. Stage H lands in buffer freed one phase earlier.
template <int TAPS, int CC, int NMT>
__global__ __launch_bounds__(512, 2) void gemm8_conv(
    const u16* __restrict__ Apack, const u16* __restrict__ Bsrc,
    const float* __restrict__ bias, u16* __restrict__ out, int M) {
  constexpr int KT = TAPS * CC / 64;
  constexpr int KT2 = 2 * KT;
  __shared__ u16 lds[65536];
  const int tid = threadIdx.x;
  const int w = tid >> 6, lane = tid & 63;
  const int wm = w >> 2, wn = w & 3;
  const int kg = lane >> 4, lm = lane & 15;
  // nt-banded XCD swizzle: XCD j owns nt in [8j, 8j+8), all mt (mt fastest).
  const int g = blockIdx.x;
  const int local = g >> 3;
  const int mt = local % NMT;
  const int nt = (g & 7) * 8 + local / NMT;
  const int b_img = nt >> 4;
  const int y0 = (nt & 15) * 4;
  const u16* Abase = Apack + (size_t)mt * KT2 * 8192;

  f32x4 acc[8][4];
  const f32x4 fz = {0.f, 0.f, 0.f, 0.f};
#pragma unroll
  for (int i = 0; i < 8; ++i)
#pragma unroll
    for (int j = 0; j < 4; ++j) acc[i][j] = fz;

  auto rbase = [&](int b, int op, int kh) -> unsigned {
    return (unsigned)(((b * 2 + op) * 2 + kh) * 8192);
  };
  auto stage = [&](int H, int op) {
    if (H >= KT2) return;
    const unsigned dstb = rbase((H >> 1) & 1, op, H & 1);
#pragma unroll
    for (int it = 0; it < 2; ++it) {
      const int d = it * 512 + tid;
      u16* ldst = (u16*)&lds[dstb + (unsigned)(it * 512 + (tid & ~63)) * 8];
      if (op == 0) {
        gload16(Abase + (size_t)H * 8192 + (size_t)d * 8, ldst);
      } else {
        const int pl = d >> 2, kq = d & 3;
        const int kglob = H * 32;
        const int tap = (TAPS == 1) ? 0 : (kglob / CC);
        const int cbase = kglob - tap * CC;
        const int ky = (TAPS == 9) ? tap / 3 : 0, kx = (TAPS == 9) ? tap % 3 : 0;
        const int r = pl >> 6, xc = pl & 63;
        const size_t gb = ((size_t)((b_img * 66 + y0 + r + ky) * 66 + (xc + kx))) * CC +
                          (size_t)(cbase + ((kq ^ ((pl >> 1) & 3)) * 8));
        gload16(Bsrc + gb, ldst);
      }
    }
  };

#define PHASE(MG_, KH_, STH_, STOP_, WAIT_)                                          \
  {                                                                                  \
    const unsigned regA = rbase(bi, 0, KH_);                                         \
    if (MG_ == 0) {                                                                  \
      const unsigned regB = rbase(bi, 1, KH_);                                       \
      _Pragma("unroll") for (int nf = 0; nf < 4; ++nf) {                             \
        const int pc = wn * 64 + nf * 16 + lm;                                       \
        bfrag[nf] = *(const bf16x8*)&lds[regB + pc * 32 + (kg ^ ((pc >> 1) & 3)) * 8]; \
      }                                                                              \
    }                                                                                \
    bf16x8 afrag[4];                                                                 \
    _Pragma("unroll") for (int f = 0; f < 4; ++f) {                                  \
      const int row = wm * 128 + (MG_ * 4 + f) * 16 + lm;                            \
      afrag[f] = *(const bf16x8*)&lds[regA + row * 32 + (kg ^ ((row >> 1) & 3)) * 8];  \
    }                                                                                \
    stage(STH_, STOP_);                                                              \
    BAR();                                                                           \
    LGK0();                                                                          \
    __builtin_amdgcn_s_setprio(1);                                                   \
    _Pragma("unroll") for (int f = 0; f < 4; ++f)                                    \
        _Pragma("unroll") for (int nf = 0; nf < 4; ++nf)                             \
            acc[MG_ * 4 + f][nf] = __builtin_amdgcn_mfma_f32_16x16x32_bf16(          \
                afrag[f], bfrag[nf], acc[MG_ * 4 + f][nf], 0, 0, 0);                 \
    __builtin_amdgcn_s_setprio(0);                                                   \
    WAIT_;                                                                           \
    BAR();                                                                           \
  }

  // Prologue: halves 0,0 / 1,1 / 2 (A,B interleaved, oldest first).
  stage(0, 0); stage(0, 1);
  stage(1, 0); stage(1, 1);
  stage(2, 0); stage(2, 1);
  VM8();   // retires halves 0 (A0,B0); halves 1-2 stay in flight
  BAR();

  for (int t = 0; t < KT; ++t) {
    const int bi = t & 1;
    bf16x8 bfrag[4];
    PHASE(0, 0, 2 * t + 3, 0, (void)0);
    PHASE(1, 0, 2 * t + 3, 1, do { if (t == KT - 1) VM0(); else VM8(); } while (0));
    PHASE(0, 1, 2 * t + 4, 0, (void)0);
    PHASE(1, 1, 2 * t + 4, 1,
          do { if (t == KT - 2) VM4(); else if (t < KT - 2) VM8(); } while (0));
  }
#undef PHASE

  // Epilogue: +bias -> fp16 offsets, NHWC [pix][M].
  const int ocb = mt * 256 + wm * 128 + kg * 4;
#pragma unroll
  for (int mf = 0; mf < 8; ++mf) {
    const int oc0 = ocb + mf * 16;
    const f32x4 bv = *(const f32x4*)&bias[oc0];
#pragma unroll
    for (int nf = 0; nf < 4; ++nf) {
      const int pix = nt * 256 + wn * 64 + nf * 16 + lm;
      f32x4 r = acc[mf][nf] + bv;
      uint2 hv;
      hv.x = (unsigned)f2h(r[0]) | ((unsigned)f2h(r[1]) << 16);
      hv.y = (unsigned)f2h(r[2]) | ((unsigned)f2h(r[3]) << 16);
      *(uint2*)(out + (size_t)pix * M + oc0) = hv;
    }
  }
}

// ================= 128^2 kernel (main path, unchanged) =================
template <int TAPS, int PAD, int EPI, int CC, int WSPLIT>
__global__ __launch_bounds__(256, 2) void gemm_conv(
    const u16* __restrict__ Aph, const u16* __restrict__ Apl,
    const u16* __restrict__ Bh,
    const float* __restrict__ p0, const float* __restrict__ p1,
    const float* __restrict__ p2, const float* __restrict__ p3,
    float* __restrict__ outF, u16* __restrict__ o16a, int M) {
  constexpr int NB = 2 + WSPLIT;
  __shared__ u16 lds[NB * 4096];
  constexpr int steps = TAPS * (CC / 32);
  const int tid = threadIdx.x;
  const int w = tid >> 6, lane = tid & 63;
  const int wm = (w >> 1) * 64, wn = (w & 1) * 64;
  const int kg = lane >> 4, lm = lane & 15;
  const int wg = blockIdx.x;
  const int chunk = (int)(gridDim.x >> 3);
  const int g = (wg & 7) * chunk + (wg >> 3);
  const int mt = g >> 7, nt = g & 127;
  const int b_img = nt >> 5;
  const int y0 = (nt & 31) * 2;

  f32x4 acc[4][4];
  const f32x4 fz = {0.f, 0.f, 0.f, 0.f};
#pragma unroll
  for (int i = 0; i < 4; ++i)
#pragma unroll
    for (int j = 0; j < 4; ++j) acc[i][j] = fz;

  const u16* Abase_h = Aph + (size_t)mt * steps * 4096;
  const u16* Abase_l = WSPLIT ? (Apl + (size_t)mt * steps * 4096) : nullptr;

  for (int step = 0; step < steps; ++step) {
    const int tap = (TAPS == 1) ? 0 : (step / (CC / 32));
    const int c0 = (step - tap * (CC / 32)) * 32;
    const int ky = (TAPS == 9) ? (tap / 3) : 0;
    const int kx = (TAPS == 9) ? (tap % 3) : 0;

#pragma unroll
    for (int it = 0; it < 2; ++it) {
      const int slot = w * 128 + it * 64 + lane;
      const unsigned ldso = (unsigned)(w * 128 + it * 64) * 8u;
      const size_t ga = (size_t)step * 4096 + (size_t)slot * 8;
      gload16(Abase_h + ga, &lds[0 * 4096 + ldso]);
      if (WSPLIT) gload16(Abase_l + ga, &lds[1 * 4096 + ldso]);
      const int n = slot >> 2, kq = slot & 3;
      const int kga = kq ^ ((n >> 1) & 3);
      size_t gb;
      if (PAD) {
        const int r = n >> 6, xc = n & 63;
        gb = ((size_t)((b_img * 66 + (y0 + r + ky)) * 66 + (xc + kx))) * CC +
             (size_t)(c0 + kga * 8);
      } else {
        gb = (size_t)(nt * 128 + n) * CC + (size_t)(c0 + kga * 8);
      }
      gload16(Bh + gb, &lds[(NB - 1) * 4096 + ldso]);
    }
    __syncthreads();

    bf16x8 ah[4], al[4], bh[4];
#pragma unroll
    for (int f = 0; f < 4; ++f) {
      const unsigned ao = (unsigned)(kg * 128 + wm + f * 16 + lm) * 8u;
      ah[f] = *(const bf16x8*)&lds[0 * 4096 + ao];
      if (WSPLIT) al[f] = *(const bf16x8*)&lds[1 * 4096 + ao];
      const int n = wn + f * 16 + lm;
      const unsigned bo = (unsigned)(n * 4 + (kg ^ ((n >> 1) & 3))) * 8u;
      bh[f] = *(const bf16x8*)&lds[(NB - 1) * 4096 + bo];
    }
#pragma unroll
    for (int i = 0; i < 4; ++i)
#pragma unroll
      for (int j = 0; j < 4; ++j) {
        acc[i][j] = __builtin_amdgcn_mfma_f32_16x16x32_bf16(ah[i], bh[j], acc[i][j], 0, 0, 0);
        if (WSPLIT)
          acc[i][j] = __builtin_amdgcn_mfma_f32_16x16x32_bf16(al[i], bh[j], acc[i][j], 0, 0, 0);
      }
    __syncthreads();
  }

  const int ocb = mt * 128 + wm + kg * 4;
#pragma unroll
  for (int fi = 0; fi < 4; ++fi) {
    const int oc0 = ocb + fi * 16;
    f32x4 scl, sft;
    if (EPI == 0) {
#pragma unroll
      for (int j = 0; j < 4; ++j) { scl[j] = 1.f; sft[j] = p0[oc0 + j]; }
    } else {
#pragma unroll
      for (int j = 0; j < 4; ++j) {
        const float inv = p0[oc0 + j] / sqrtf(p3[oc0 + j] + 1e-5f);
        scl[j] = inv;
        sft[j] = p1[oc0 + j] - p2[oc0 + j] * inv;
      }
    }
#pragma unroll
    for (int fj = 0; fj < 4; ++fj) {
      const int pix = nt * 128 + wn + fj * 16 + lm;
      f32x4 r = acc[fi][fj] * scl + sft;
      if (EPI == 0) {
        uint2 hv;
        hv.x = (unsigned)f2h(r[0]) | ((unsigned)f2h(r[1]) << 16);
        hv.y = (unsigned)f2h(r[2]) | ((unsigned)f2h(r[3]) << 16);
        *(uint2*)(o16a + (size_t)pix * M + oc0) = hv;
      } else if (EPI == 1) {
        const int bb = pix >> 12, yy = (pix >> 6) & 63, xx = pix & 63;
        const size_t pp = ((size_t)((bb * 66 + yy + 1) * 66 + (xx + 1))) * M + oc0;
        uint2 hv;
        hv.x = (unsigned)f2bf(r[0]) | ((unsigned)f2bf(r[1]) << 16);
        hv.y = (unsigned)f2bf(r[2]) | ((unsigned)f2bf(r[3]) << 16);
        *(uint2*)(o16a + pp) = hv;
      } else {
        const int bb = pix >> 12, pin = pix & 4095;
#pragma unroll
        for (int j = 0; j < 4; ++j)
          outF[((size_t)(bb * M + oc0 + j)) * 4096 + pin] = fmaxf(r[j], 0.f);
      }
    }
  }
}

extern "C" void kernel_launch(void* const* d_in, const int* in_sizes, int n_in,
                              void* d_out, int out_size, void* d_ws, size_t ws_size,
                              hipStream_t stream) {
  (void)in_sizes; (void)out_size;
  if (n_in < 22) return;
  const float* x   = (const float*)d_in[0];
  const float* ow1 = (const float*)d_in[1];
  const float* ob1 = (const float*)d_in[2];
  const float* ow2 = (const float*)d_in[3];
  const float* ob2 = (const float*)d_in[4];
  const float* ow3 = (const float*)d_in[5];
  const float* ob3 = (const float*)d_in[6];
  const float* w1  = (const float*)d_in[7];
  const float* w2  = (const float*)d_in[8];
  const float* w3  = (const float*)d_in[9];
  const float* g1 = (const float*)d_in[10], *b1 = (const float*)d_in[11];
  const float* m1 = (const float*)d_in[12], *v1 = (const float*)d_in[13];
  const float* g2 = (const float*)d_in[14], *b2 = (const float*)d_in[15];
  const float* m2 = (const float*)d_in[16], *v2 = (const float*)d_in[17];
  const float* g3 = (const float*)d_in[18], *b3 = (const float*)d_in[19];
  const float* m3 = (const float*)d_in[20], *v3 = (const float*)d_in[21];

  char* W = (char*)d_ws;
  // ---- workspace map: 185,630,720 B (identical to round 3; proven safe) ----
  constexpr size_t P66_1024 = 4ull * 66 * 66 * 1024 * 2;
  constexpr size_t P66_256  = 4ull * 66 * 66 * 256 * 2;
  constexpr size_t SZ_OFF1  = 4ull * 4096 * 2048 * 2;
  constexpr size_t SZ_OFF2  = 4ull * 4096 * 512 * 2;
  constexpr size_t SZ_H1    = 4ull * 4096 * 1024 * 2;
  constexpr size_t SZ_H3    = 4ull * 4096 * 256 * 2;
  constexpr size_t SZ_OW1 = 2048ull * 9216 * 2;
  constexpr size_t SZ_W1  = 256ull * 1024 * 2;
  constexpr size_t SZ_OW2 = 512ull * 2304 * 2;
  constexpr size_t SZ_W2  = 256ull * 2304 * 2;
  constexpr size_t SZ_OW3 = 512ull * 2304 * 2;
  constexpr size_t SZ_W3  = 1024ull * 256 * 2;

  constexpr size_t o_ow1h = 0;
  constexpr size_t o_xp   = o_ow1h + SZ_OW1;
  constexpr size_t o_off1 = o_xp + P66_1024;
  constexpr size_t o_t1p  = o_off1;
  constexpr size_t o_off2 = o_t1p + P66_256;
  constexpr size_t o_h2p  = o_off2 + SZ_OFF2;
  constexpr size_t o_t2p  = o_h2p + P66_256;
  static_assert(o_t2p + P66_256 <= o_off1 + SZ_OFF1, "era2 fits off1 slot");
  constexpr size_t o_h1   = o_off1 + SZ_OFF1;
  constexpr size_t o_off3 = o_h1;
  constexpr size_t o_h3   = o_off3 + SZ_OFF2;
  static_assert(o_h3 + SZ_H3 <= o_h1 + SZ_H1, "off3+h3 fit h1 slot");
  constexpr size_t o_w1h  = o_h1 + SZ_H1;
  constexpr size_t o_w1l  = o_w1h + SZ_W1;
  constexpr size_t o_ow2h = o_w1l + SZ_W1;
  constexpr size_t o_w2h  = o_ow2h + SZ_OW2;
  constexpr size_t o_w2l  = o_w2h + SZ_W2;
  constexpr size_t o_ow3h = o_w2l + SZ_W2;
  constexpr size_t o_w3h  = o_ow3h + SZ_OW3;
  constexpr size_t o_w3l  = o_w3h + SZ_W3;
  constexpr size_t WS_NEED = o_w3l + SZ_W3;
  if (ws_size < WS_NEED) return;

  auto U = [&](size_t o) { return (u16*)(W + o); };
  auto zero = [&](size_t off, size_t bytes) {
    const unsigned n = (unsigned)(bytes / 16);
    unsigned grid = (n + 255) / 256; if (grid > 4096) grid = 4096;
    zero_k<<<grid, 256, 0, stream>>>((uint4*)(W + off), n);
  };

  // ---- weight prep ----
  {
    int n;
    n = 2048 * 9216; pack8_w<1024, 9><<<(n + 255) / 256, 256, 0, stream>>>(ow1, U(o_ow1h), 2048);
    n = 512 * 2304;  pack8_w<256, 9><<<(n + 255) / 256, 256, 0, stream>>>(ow2, U(o_ow2h), 512);
    n = 512 * 2304;  pack8_w<256, 9><<<(n + 255) / 256, 256, 0, stream>>>(ow3, U(o_ow3h), 512);
    n = 256 * 1024;  pack_w<1><<<(n + 255) / 256, 256, 0, stream>>>(w1, U(o_w1h), U(o_w1l), 256, 1024, 1);
    n = 256 * 2304;  pack_w<1><<<(n + 255) / 256, 256, 0, stream>>>(w2, U(o_w2h), U(o_w2l), 256, 256, 9);
    n = 1024 * 256;  pack_w<1><<<(n + 255) / 256, 256, 0, stream>>>(w3, U(o_w3h), U(o_w3l), 1024, 256, 1);
  }

  // ---- stage 0: pad x -> bf16 ----
  zero(o_xp, P66_1024);
  prep_x<<<dim3(16, 64, 4), 256, 0, stream>>>(x, U(o_xp));

  // G1: offset-conv1 (3x3, 1024 -> 2048), 8-phase 256^2 -> off1 fp16
  gemm8_conv<9, 1024, 8><<<512, 512, 0, stream>>>(
      U(o_ow1h), U(o_xp), ob1, U(o_off1), 2048);
  // D1: deform(x, off1) -> h1
  deform_k<1024, 0><<<65536, 256, 0, stream>>>(U(o_xp), U(o_off1), U(o_h1));

  zero(o_t1p, P66_256);
  zero(o_h2p, 2 * P66_256);
  // G2: conv1 1x1 + BN1 -> t1 padded bf16
  gemm_conv<1, 0, 1, 1024, 1><<<256, 256, 0, stream>>>(
      U(o_w1h), U(o_w1l), U(o_h1), g1, b1, m1, v1, nullptr, U(o_t1p), 256);
  // G3: offset-conv2, 8-phase -> off2 fp16
  gemm8_conv<9, 256, 2><<<128, 512, 0, stream>>>(
      U(o_ow2h), U(o_t1p), ob2, U(o_off2), 512);
  // D2: deform(t1, off2) -> h2 padded
  deform_k<256, 1><<<16384, 256, 0, stream>>>(U(o_t1p), U(o_off2), U(o_h2p));
  // G4: conv2 3x3 + BN2 -> t2 padded bf16
  gemm_conv<9, 1, 1, 256, 1><<<256, 256, 0, stream>>>(
      U(o_w2h), U(o_w2l), U(o_h2p), g2, b2, m2, v2, nullptr, U(o_t2p), 256);
  // G5: offset-conv3, 8-phase -> off3 fp16
  gemm8_conv<9, 256, 2><<<128, 512, 0, stream>>>(
      U(o_ow3h), U(o_t2p), ob3, U(o_off3), 512);
  // D3: deform(t2, off3) -> h3
  deform_k<256, 0><<<16384, 256, 0, stream>>>(U(o_t2p), U(o_off3), U(o_h3));
  // G6: conv3 1x1 + BN3 + ReLU -> d_out (NCHW fp32)
  gemm_conv<1, 0, 2, 256, 1><<<1024, 256, 0, stream>>>(
      U(o_w3h), U(o_w3l), U(o_h3), g3, b3, m3, v3, (float*)d_out, nullptr, 1024);
}

// Round 6
// 1056.096 us; speedup vs baseline: 2.6519x; 1.0683x over previous
//
#include <hip/hip_runtime.h>

// Deformable bottleneck block, MI355X/gfx950.  Round 5 (resubmit; round-5 bench
// never ran: GPU acquisition timeout).
// G1 (offset-conv1, 50% of runtime): 256^2 8-phase kernel with 1-phase
// read-ahead software pipeline (frags for phase p+1 issued before phase p's
// MFMA, so the LDS-read backlog drains UNDER the MFMA window instead of
// between barriers). Counted vmcnt ledger: VM8 prologue, VM6 at sub0/sub2
// retiring exactly one half each, VM0 for the last 2 tiles. 1 barrier/phase.
// G3/G5: 128^2 kernel (grid 512; the 8-phase grid of 128 idled half the GPU).
// G2/G4/G6: weight hi/lo split dropped (activations already bf16; exact
// weights only buy sqrt(2) on error) -> 1 MFMA each.

typedef unsigned short u16;
typedef __bf16 bf16x8 __attribute__((ext_vector_type(8)));
typedef float f32x4 __attribute__((ext_vector_type(4)));
typedef _Float16 f16;

__device__ __forceinline__ u16 f2bf(float f) {
  unsigned u = __float_as_uint(f);
  u += 0x7fffu + ((u >> 16) & 1u);
  return (u16)(u >> 16);
}
__device__ __forceinline__ float bf2f(u16 h) { return __uint_as_float((unsigned)h << 16); }
__device__ __forceinline__ u16 f2h(float f) { f16 h = (f16)f; return __builtin_bit_cast(u16, h); }
__device__ __forceinline__ float h2f(u16 u) { return (float)__builtin_bit_cast(f16, u); }

__device__ __forceinline__ void gload16(const u16* g, u16* l) {
  __builtin_amdgcn_global_load_lds((__attribute__((address_space(1))) unsigned int*)g,
                                   (__attribute__((address_space(3))) unsigned int*)l,
                                   16, 0, 0);
}

#define VM8() asm volatile("s_waitcnt vmcnt(8)" ::: "memory")
#define VM6() asm volatile("s_waitcnt vmcnt(6)" ::: "memory")
#define VM0() asm volatile("s_waitcnt vmcnt(0)" ::: "memory")
#define BAR()                                   \
  do {                                          \
    asm volatile("" ::: "memory");              \
    __builtin_amdgcn_s_barrier();               \
    asm volatile("" ::: "memory");              \
  } while (0)
#define LGK0()                                          \
  do {                                                  \
    asm volatile("s_waitcnt lgkmcnt(0)" ::: "memory");  \
    __builtin_amdgcn_sched_barrier(0);                  \
  } while (0)
#define SB0() __builtin_amdgcn_sched_barrier(0)

__global__ __launch_bounds__(256) void zero_k(uint4* __restrict__ p, unsigned n) {
  unsigned i = blockIdx.x * 256u + threadIdx.x;
  const unsigned st = gridDim.x * 256u;
  uint4 z; z.x = 0u; z.y = 0u; z.z = 0u; z.w = 0u;
  for (; i < n; i += st) p[i] = z;
}

// ---- 128^2-kernel weight pack: [M/128][K/32][kg][m][8], K tap-major ----
template <int SPLIT>
__global__ __launch_bounds__(256) void pack_w(const float* __restrict__ w,
                                              u16* __restrict__ hi, u16* __restrict__ lo,
                                              int M, int C, int T) {
  const int AK = C * T;
  const int id = blockIdx.x * 256 + threadIdx.x;
  if (id >= M * AK) return;
  const int j = id & 7;
  const int slot = (id >> 3) & 511;
  const int rest = id >> 12;
  const int steps = AK >> 5;
  const int step = rest % steps;
  const int mt = rest / steps;
  const int kg = slot >> 7, m = slot & 127;
  const int k = step * 32 + kg * 8 + j;
  const int tap = k / C;
  const int c = k - tap * C;
  const int mg = mt * 128 + m;
  const float v = w[((size_t)mg * C + c) * T + tap];
  const u16 h = f2bf(v);
  hi[id] = h;
  if (SPLIT) lo[id] = f2bf(v - bf2f(h));
}

// ---- 256^2 kernel weight pack: [mt][half H][slot d][8], read-XOR baked in ----
template <int CC, int T>
__global__ __launch_bounds__(256) void pack8_w(const float* __restrict__ w,
                                               u16* __restrict__ dst, int M) {
  constexpr int KT2 = 2 * (T * CC / 64);
  const int id = blockIdx.x * 256 + threadIdx.x;
  if (id >= M * CC * T) return;
  const int j = id & 7;
  const int d = (id >> 3) & 1023;
  const int rest = id >> 13;
  const int H = rest % KT2;
  const int mt = rest / KT2;
  const int row = d >> 2, kq = d & 3;
  const int k = H * 32 + ((kq ^ ((row >> 1) & 3)) * 8) + j;
  const int tap = k / CC, c = k - tap * CC;
  const int oc = mt * 256 + row;
  dst[id] = f2bf(w[((size_t)oc * CC + c) * T + tap]);
}

// x NCHW fp32 -> padded bf16 [4][66][66][1024]
__global__ __launch_bounds__(256) void prep_x(const float* __restrict__ x,
                                              u16* __restrict__ xp) {
  __shared__ float t[64][65];
  const int c0 = blockIdx.x * 64;
  const int y = blockIdx.y;
  const int b = blockIdx.z;
  const int tid = threadIdx.x;
#pragma unroll
  for (int i = 0; i < 16; ++i) {
    const int idx = i * 256 + tid;
    const int ci = idx >> 6, xi = idx & 63;
    t[ci][xi] = x[(((size_t)b * 1024 + c0 + ci) * 64 + y) * 64 + xi];
  }
  __syncthreads();
#pragma unroll
  for (int i = 0; i < 16; ++i) {
    const int idx = i * 256 + tid;
    const int xi = idx >> 6, ci = idx & 63;
    xp[((size_t)((b * 66 + y + 1) * 66 + (xi + 1))) * 1024 + c0 + ci] = f2bf(t[ci][xi]);
  }
}

// Bilinear resample (per-channel offsets), unchanged.
template <int C, int PADDST>
__global__ __launch_bounds__(256) void deform_k(const u16* __restrict__ src,
                                                const u16* __restrict__ off,
                                                u16* __restrict__ dst) {
  const int id = blockIdx.x * 256 + threadIdx.x;
  const int c = id & (C - 1);
  const int pix = id / C;
  const int b = pix >> 12;
  const int y = (pix >> 6) & 63;
  const int x = pix & 63;
  const unsigned ov = *(const unsigned*)(off + (size_t)pix * (2 * C) + 2 * c);
  const float py = fminf(fmaxf((float)y + h2f((u16)(ov & 0xffffu)), 0.f), 63.f);
  const float px = fminf(fmaxf((float)x + h2f((u16)(ov >> 16)), 0.f), 63.f);
  const int y0i = (int)py, x0i = (int)px;
  const int y1i = min(y0i + 1, 63), x1i = min(x0i + 1, 63);
  const float wy = py - (float)y0i, wx = px - (float)x0i;
  const int bb66 = b * 66;
  auto at = [&](int yi, int xi) -> size_t {
    return ((size_t)((bb66 + yi + 1) * 66 + (xi + 1))) * C + c;
  };
  const float v00 = bf2f(src[at(y0i, x0i)]);
  const float v01 = bf2f(src[at(y0i, x1i)]);
  const float v10 = bf2f(src[at(y1i, x0i)]);
  const float v11 = bf2f(src[at(y1i, x1i)]);
  const float val = v00 * (1.f - wy) * (1.f - wx) + v01 * (1.f - wy) * wx +
                    v10 * wy * (1.f - wx) + v11 * wy * wx;
  const size_t d = PADDST ? at(y, x) : (size_t)id;
  dst[d] = f2bf(val);
}

// ================= 256^2 8-phase pipelined offset-conv GEMM =================
// BM=BN=256, BK=64, 8 waves (2Mx4N), LDS 128 KiB = buf[2] x {A,B} x kh[2].
// Read-ahead=1: frags for phase p+1 are ds_read during phase p (before its
// MFMA cluster), so LGK0 at p+1 is ~free. Stage schedule identical to round 4
// (sub0:A(2t+3), sub1:B(2t+3), sub2:A(2t+4), sub3:B(2t+4)); VM6 at sub0/sub2
// retires exactly one half (4 loads) 1.5 phases before its first read.
template <int TAPS, int CC, int NMT>
__global__ __launch_bounds__(512, 2) void gemm8_conv(
    const u16* __restrict__ Apack, const u16* __restrict__ Bsrc,
    const float* __restrict__ bias, u16* __restrict__ out, int M) {
  constexpr int KT = TAPS * CC / 64;
  constexpr int KT2 = 2 * KT;
  __shared__ u16 lds[65536];
  const int tid = threadIdx.x;
  const int w = tid >> 6, lane = tid & 63;
  const int wm = w >> 2, wn = w & 3;
  const int kg = lane >> 4, lm = lane & 15;
  // nt-banded XCD swizzle: XCD j owns nt in [8j, 8j+8), mt fastest.
  const int g = blockIdx.x;
  const int local = g >> 3;
  const int mt = local % NMT;
  const int nt = (g & 7) * 8 + local / NMT;
  const int b_img = nt >> 4;
  const int y0 = (nt & 15) * 4;

  // saddr-style staging: per-lane offsets precomputed, per-phase scalar base.
  int laneA[2], laneB[2];
  unsigned ldsoff[2];
#pragma unroll
  for (int it = 0; it < 2; ++it) {
    const int d = it * 512 + tid;
    laneA[it] = d * 8;
    const int pl = d >> 2, kq = d & 3;
    const int r = pl >> 6, xc = pl & 63;
    laneB[it] = (r * 66 + xc) * CC + (kq ^ ((pl >> 1) & 3)) * 8;
    ldsoff[it] = (unsigned)(it * 512 + (tid & ~63)) * 8u;
  }
  const u16* Abase = Apack + (size_t)mt * KT2 * 8192;
  const u16* Bbase = Bsrc + (size_t)(b_img * 66 + y0) * 66 * CC;

  f32x4 acc[8][4];
  const f32x4 fz = {0.f, 0.f, 0.f, 0.f};
#pragma unroll
  for (int i = 0; i < 8; ++i)
#pragma unroll
    for (int j = 0; j < 4; ++j) acc[i][j] = fz;

  auto rbase = [&](int b, int op, int kh) -> unsigned {
    return (unsigned)(((b * 2 + op) * 2 + kh) * 8192);
  };
  auto stageA = [&](int H) {
    if (H >= KT2) return;
    const u16* p = Abase + (size_t)H * 8192;
    const unsigned db = rbase((H >> 1) & 1, 0, H & 1);
    gload16(p + laneA[0], (u16*)&lds[db + ldsoff[0]]);
    gload16(p + laneA[1], (u16*)&lds[db + ldsoff[1]]);
  };
  auto stageB = [&](int H) {
    if (H >= KT2) return;
    const int kglob = H * 32;
    const int tap = (TAPS == 1) ? 0 : (kglob / CC);
    const int cbase = kglob - tap * CC;
    const int ky = (TAPS == 9) ? tap / 3 : 0, kx = (TAPS == 9) ? tap % 3 : 0;
    const u16* p = Bbase + (ky * 66 + kx) * CC + cbase;
    const unsigned db = rbase((H >> 1) & 1, 1, H & 1);
    gload16(p + laneB[0], (u16*)&lds[db + ldsoff[0]]);
    gload16(p + laneB[1], (u16*)&lds[db + ldsoff[1]]);
  };

  bf16x8 afE[4], afO[4], bfA[4], bfB[4];
  auto rdA = [&](bf16x8* dst, int buf, int kh, int MG) {
    const unsigned regA = rbase(buf, 0, kh);
#pragma unroll
    for (int f = 0; f < 4; ++f) {
      const int row = wm * 128 + (MG * 4 + f) * 16 + lm;
      dst[f] = *(const bf16x8*)&lds[regA + row * 32 + (kg ^ ((row >> 1) & 3)) * 8];
    }
  };
  auto rdB = [&](bf16x8* dst, int buf, int kh) {
    const unsigned regB = rbase(buf, 1, kh);
#pragma unroll
    for (int f = 0; f < 4; ++f) {
      const int pc = wn * 64 + f * 16 + lm;
      dst[f] = *(const bf16x8*)&lds[regB + pc * 32 + (kg ^ ((pc >> 1) & 3)) * 8];
    }
  };

#define MFMA16(MG_, AF_, BF_)                                                        \
  do {                                                                               \
    __builtin_amdgcn_s_setprio(1);                                                   \
    _Pragma("unroll") for (int f = 0; f < 4; ++f)                                    \
        _Pragma("unroll") for (int nf = 0; nf < 4; ++nf)                             \
            acc[MG_ * 4 + f][nf] = __builtin_amdgcn_mfma_f32_16x16x32_bf16(          \
                AF_[f], BF_[nf], acc[MG_ * 4 + f][nf], 0, 0, 0);                     \
    __builtin_amdgcn_s_setprio(0);                                                   \
  } while (0)

  // Prologue: stage halves 0..2 (12 loads); VM8 retires half 0; pre-read p=0.
  stageA(0); stageB(0);
  stageA(1); stageB(1);
  stageA(2); stageB(2);
  VM8();
  BAR();
  rdA(afE, 0, 0, 0);
  rdB(bfA, 0, 0);

  for (int t = 0; t < KT; ++t) {
    const int bi = t & 1;
    // ---- sub0: MFMA(MG0,kh0) = afE x bfA ----
    LGK0();
    rdA(afO, bi, 0, 1);          // frags for sub1
    stageA(2 * t + 3);
    SB0();
    MFMA16(0, afE, bfA);
    if (t >= KT - 2) VM0(); else VM6();   // retires half 2t+1 (kh1)
    BAR();
    // ---- sub1: MFMA(MG1,kh0) = afO x bfA ----
    LGK0();
    rdA(afE, bi, 1, 0);          // frags for sub2 (kh1)
    rdB(bfB, bi, 1);
    stageB(2 * t + 3);
    SB0();
    MFMA16(1, afO, bfA);
    BAR();
    // ---- sub2: MFMA(MG0,kh1) = afE x bfB ----
    LGK0();
    rdA(afO, bi, 1, 1);          // frags for sub3
    stageA(2 * t + 4);
    SB0();
    MFMA16(0, afE, bfB);
    if (t < KT - 2) VM6();                // retires half 2t+2 (next-buf kh0)
    BAR();
    // ---- sub3: MFMA(MG1,kh1) = afO x bfB ----
    LGK0();
    if (t + 1 < KT) {
      rdA(afE, bi ^ 1, 0, 0);    // frags for (t+1).sub0
      rdB(bfA, bi ^ 1, 0);
    }
    stageB(2 * t + 4);
    SB0();
    MFMA16(1, afO, bfB);
    BAR();
  }
#undef MFMA16

  // Epilogue: +bias -> fp16 offsets, NHWC [pix][M]. 16x16 C/D layout.
  const int ocb = mt * 256 + wm * 128 + kg * 4;
#pragma unroll
  for (int mf = 0; mf < 8; ++mf) {
    const int oc0 = ocb + mf * 16;
    const f32x4 bv = *(const f32x4*)&bias[oc0];
#pragma unroll
    for (int nf = 0; nf < 4; ++nf) {
      const int pix = nt * 256 + wn * 64 + nf * 16 + lm;
      f32x4 r = acc[mf][nf] + bv;
      uint2 hv;
      hv.x = (unsigned)f2h(r[0]) | ((unsigned)f2h(r[1]) << 16);
      hv.y = (unsigned)f2h(r[2]) | ((unsigned)f2h(r[3]) << 16);
      *(uint2*)(out + (size_t)pix * M + oc0) = hv;
    }
  }
}

// ================= 128^2 kernel (proven; used for G2..G6) =================
template <int TAPS, int PAD, int EPI, int CC, int WSPLIT>
__global__ __launch_bounds__(256, 2) void gemm_conv(
    const u16* __restrict__ Aph, const u16* __restrict__ Apl,
    const u16* __restrict__ Bh,
    const float* __restrict__ p0, const float* __restrict__ p1,
    const float* __restrict__ p2, const float* __restrict__ p3,
    float* __restrict__ outF, u16* __restrict__ o16a, int M) {
  constexpr int NB = 2 + WSPLIT;
  __shared__ u16 lds[NB * 4096];
  constexpr int steps = TAPS * (CC / 32);
  const int tid = threadIdx.x;
  const int w = tid >> 6, lane = tid & 63;
  const int wm = (w >> 1) * 64, wn = (w & 1) * 64;
  const int kg = lane >> 4, lm = lane & 15;
  const int wg = blockIdx.x;
  const int chunk = (int)(gridDim.x >> 3);
  const int g = (wg & 7) * chunk + (wg >> 3);
  const int mt = g >> 7, nt = g & 127;
  const int b_img = nt >> 5;
  const int y0 = (nt & 31) * 2;

  f32x4 acc[4][4];
  const f32x4 fz = {0.f, 0.f, 0.f, 0.f};
#pragma unroll
  for (int i = 0; i < 4; ++i)
#pragma unroll
    for (int j = 0; j < 4; ++j) acc[i][j] = fz;

  const u16* Abase_h = Aph + (size_t)mt * steps * 4096;
  const u16* Abase_l = WSPLIT ? (Apl + (size_t)mt * steps * 4096) : nullptr;

  for (int step = 0; step < steps; ++step) {
    const int tap = (TAPS == 1) ? 0 : (step / (CC / 32));
    const int c0 = (step - tap * (CC / 32)) * 32;
    const int ky = (TAPS == 9) ? (tap / 3) : 0;
    const int kx = (TAPS == 9) ? (tap % 3) : 0;

#pragma unroll
    for (int it = 0; it < 2; ++it) {
      const int slot = w * 128 + it * 64 + lane;
      const unsigned ldso = (unsigned)(w * 128 + it * 64) * 8u;
      const size_t ga = (size_t)step * 4096 + (size_t)slot * 8;
      gload16(Abase_h + ga, &lds[0 * 4096 + ldso]);
      if (WSPLIT) gload16(Abase_l + ga, &lds[1 * 4096 + ldso]);
      const int n = slot >> 2, kq = slot & 3;
      const int kga = kq ^ ((n >> 1) & 3);
      size_t gb;
      if (PAD) {
        const int r = n >> 6, xc = n & 63;
        gb = ((size_t)((b_img * 66 + (y0 + r + ky)) * 66 + (xc + kx))) * CC +
             (size_t)(c0 + kga * 8);
      } else {
        gb = (size_t)(nt * 128 + n) * CC + (size_t)(c0 + kga * 8);
      }
      gload16(Bh + gb, &lds[(NB - 1) * 4096 + ldso]);
    }
    __syncthreads();

    bf16x8 ah[4], al[4], bh[4];
#pragma unroll
    for (int f = 0; f < 4; ++f) {
      const unsigned ao = (unsigned)(kg * 128 + wm + f * 16 + lm) * 8u;
      ah[f] = *(const bf16x8*)&lds[0 * 4096 + ao];
      if (WSPLIT) al[f] = *(const bf16x8*)&lds[1 * 4096 + ao];
      const int n = wn + f * 16 + lm;
      const unsigned bo = (unsigned)(n * 4 + (kg ^ ((n >> 1) & 3))) * 8u;
      bh[f] = *(const bf16x8*)&lds[(NB - 1) * 4096 + bo];
    }
#pragma unroll
    for (int i = 0; i < 4; ++i)
#pragma unroll
      for (int j = 0; j < 4; ++j) {
        acc[i][j] = __builtin_amdgcn_mfma_f32_16x16x32_bf16(ah[i], bh[j], acc[i][j], 0, 0, 0);
        if (WSPLIT)
          acc[i][j] = __builtin_amdgcn_mfma_f32_16x16x32_bf16(al[i], bh[j], acc[i][j], 0, 0, 0);
      }
    __syncthreads();
  }

  const int ocb = mt * 128 + wm + kg * 4;
#pragma unroll
  for (int fi = 0; fi < 4; ++fi) {
    const int oc0 = ocb + fi * 16;
    f32x4 scl, sft;
    if (EPI == 0) {
#pragma unroll
      for (int j = 0; j < 4; ++j) { scl[j] = 1.f; sft[j] = p0[oc0 + j]; }
    } else {
#pragma unroll
      for (int j = 0; j < 4; ++j) {
        const float inv = p0[oc0 + j] / sqrtf(p3[oc0 + j] + 1e-5f);
        scl[j] = inv;
        sft[j] = p1[oc0 + j] - p2[oc0 + j] * inv;
      }
    }
#pragma unroll
    for (int fj = 0; fj < 4; ++fj) {
      const int pix = nt * 128 + wn + fj * 16 + lm;
      f32x4 r = acc[fi][fj] * scl + sft;
      if (EPI == 0) {
        uint2 hv;
        hv.x = (unsigned)f2h(r[0]) | ((unsigned)f2h(r[1]) << 16);
        hv.y = (unsigned)f2h(r[2]) | ((unsigned)f2h(r[3]) << 16);
        *(uint2*)(o16a + (size_t)pix * M + oc0) = hv;
      } else if (EPI == 1) {
        const int bb = pix >> 12, yy = (pix >> 6) & 63, xx = pix & 63;
        const size_t pp = ((size_t)((bb * 66 + yy + 1) * 66 + (xx + 1))) * M + oc0;
        uint2 hv;
        hv.x = (unsigned)f2bf(r[0]) | ((unsigned)f2bf(r[1]) << 16);
        hv.y = (unsigned)f2bf(r[2]) | ((unsigned)f2bf(r[3]) << 16);
        *(uint2*)(o16a + pp) = hv;
      } else {
        const int bb = pix >> 12, pin = pix & 4095;
#pragma unroll
        for (int j = 0; j < 4; ++j)
          outF[((size_t)(bb * M + oc0 + j)) * 4096 + pin] = fmaxf(r[j], 0.f);
      }
    }
  }
}

extern "C" void kernel_launch(void* const* d_in, const int* in_sizes, int n_in,
                              void* d_out, int out_size, void* d_ws, size_t ws_size,
                              hipStream_t stream) {
  (void)in_sizes; (void)out_size;
  if (n_in < 22) return;
  const float* x   = (const float*)d_in[0];
  const float* ow1 = (const float*)d_in[1];
  const float* ob1 = (const float*)d_in[2];
  const float* ow2 = (const float*)d_in[3];
  const float* ob2 = (const float*)d_in[4];
  const float* ow3 = (const float*)d_in[5];
  const float* ob3 = (const float*)d_in[6];
  const float* w1  = (const float*)d_in[7];
  const float* w2  = (const float*)d_in[8];
  const float* w3  = (const float*)d_in[9];
  const float* g1 = (const float*)d_in[10], *b1 = (const float*)d_in[11];
  const float* m1 = (const float*)d_in[12], *v1 = (const float*)d_in[13];
  const float* g2 = (const float*)d_in[14], *b2 = (const float*)d_in[15];
  const float* m2 = (const float*)d_in[16], *v2 = (const float*)d_in[17];
  const float* g3 = (const float*)d_in[18], *b3 = (const float*)d_in[19];
  const float* m3 = (const float*)d_in[20], *v3 = (const float*)d_in[21];

  char* W = (char*)d_ws;
  // ---- workspace map: 181,043,200 B (prior 185.6 MB proven safe) ----
  constexpr size_t P66_1024 = 4ull * 66 * 66 * 1024 * 2;
  constexpr size_t P66_256  = 4ull * 66 * 66 * 256 * 2;
  constexpr size_t SZ_OFF1  = 4ull * 4096 * 2048 * 2;
  constexpr size_t SZ_OFF2  = 4ull * 4096 * 512 * 2;
  constexpr size_t SZ_H1    = 4ull * 4096 * 1024 * 2;
  constexpr size_t SZ_H3    = 4ull * 4096 * 256 * 2;
  constexpr size_t SZ_OW1 = 2048ull * 9216 * 2;
  constexpr size_t SZ_W1  = 256ull * 1024 * 2;
  constexpr size_t SZ_OW2 = 512ull * 2304 * 2;
  constexpr size_t SZ_W2  = 256ull * 2304 * 2;
  constexpr size_t SZ_OW3 = 512ull * 2304 * 2;
  constexpr size_t SZ_W3  = 1024ull * 256 * 2;

  constexpr size_t o_ow1h = 0;
  constexpr size_t o_xp   = o_ow1h + SZ_OW1;
  constexpr size_t o_off1 = o_xp + P66_1024;
  constexpr size_t o_t1p  = o_off1;
  constexpr size_t o_off2 = o_t1p + P66_256;
  constexpr size_t o_h2p  = o_off2 + SZ_OFF2;
  constexpr size_t o_t2p  = o_h2p + P66_256;
  static_assert(o_t2p + P66_256 <= o_off1 + SZ_OFF1, "era2 fits off1 slot");
  constexpr size_t o_h1   = o_off1 + SZ_OFF1;
  constexpr size_t o_off3 = o_h1;
  constexpr size_t o_h3   = o_off3 + SZ_OFF2;
  static_assert(o_h3 + SZ_H3 <= o_h1 + SZ_H1, "off3+h3 fit h1 slot");
  constexpr size_t o_w1h  = o_h1 + SZ_H1;
  constexpr size_t o_ow2h = o_w1h + SZ_W1;
  constexpr size_t o_w2h  = o_ow2h + SZ_OW2;
  constexpr size_t o_ow3h = o_w2h + SZ_W2;
  constexpr size_t o_w3h  = o_ow3h + SZ_OW3;
  constexpr size_t WS_NEED = o_w3h + SZ_W3;   // 181,043,200
  if (ws_size < WS_NEED) return;

  auto U = [&](size_t o) { return (u16*)(W + o); };
  auto zero = [&](size_t off, size_t bytes) {
    const unsigned n = (unsigned)(bytes / 16);
    unsigned grid = (n + 255) / 256; if (grid > 4096) grid = 4096;
    zero_k<<<grid, 256, 0, stream>>>((uint4*)(W + off), n);
  };

  // ---- weight prep (re-done every call; ws is re-poisoned) ----
  {
    int n;
    n = 2048 * 9216; pack8_w<1024, 9><<<(n + 255) / 256, 256, 0, stream>>>(ow1, U(o_ow1h), 2048);
    n = 512 * 2304;  pack_w<0><<<(n + 255) / 256, 256, 0, stream>>>(ow2, U(o_ow2h), nullptr, 512, 256, 9);
    n = 512 * 2304;  pack_w<0><<<(n + 255) / 256, 256, 0, stream>>>(ow3, U(o_ow3h), nullptr, 512, 256, 9);
    n = 256 * 1024;  pack_w<0><<<(n + 255) / 256, 256, 0, stream>>>(w1, U(o_w1h), nullptr, 256, 1024, 1);
    n = 256 * 2304;  pack_w<0><<<(n + 255) / 256, 256, 0, stream>>>(w2, U(o_w2h), nullptr, 256, 256, 9);
    n = 1024 * 256;  pack_w<0><<<(n + 255) / 256, 256, 0, stream>>>(w3, U(o_w3h), nullptr, 1024, 256, 1);
  }

  // ---- stage 0: pad x -> bf16 ----
  zero(o_xp, P66_1024);
  prep_x<<<dim3(16, 64, 4), 256, 0, stream>>>(x, U(o_xp));

  // G1: offset-conv1 (3x3, 1024 -> 2048), pipelined 8-phase -> off1 fp16
  gemm8_conv<9, 1024, 8><<<512, 512, 0, stream>>>(
      U(o_ow1h), U(o_xp), ob1, U(o_off1), 2048);
  // D1: deform(x, off1) -> h1
  deform_k<1024, 0><<<65536, 256, 0, stream>>>(U(o_xp), U(o_off1), U(o_h1));

  zero(o_t1p, P66_256);
  zero(o_h2p, 2 * P66_256);
  // G2: conv1 1x1 + BN1 -> t1 padded bf16
  gemm_conv<1, 0, 1, 1024, 0><<<256, 256, 0, stream>>>(
      U(o_w1h), nullptr, U(o_h1), g1, b1, m1, v1, nullptr, U(o_t1p), 256);
  // G3: offset-conv2 (3x3, 256 -> 512) -> off2 fp16
  gemm_conv<9, 1, 0, 256, 0><<<512, 256, 0, stream>>>(
      U(o_ow2h), nullptr, U(o_t1p), ob2, nullptr, nullptr, nullptr,
      nullptr, U(o_off2), 512);
  // D2: deform(t1, off2) -> h2 padded
  deform_k<256, 1><<<16384, 256, 0, stream>>>(U(o_t1p), U(o_off2), U(o_h2p));
  // G4: conv2 3x3 + BN2 -> t2 padded bf16
  gemm_conv<9, 1, 1, 256, 0><<<256, 256, 0, stream>>>(
      U(o_w2h), nullptr, U(o_h2p), g2, b2, m2, v2, nullptr, U(o_t2p), 256);
  // G5: offset-conv3 -> off3 fp16
  gemm_conv<9, 1, 0, 256, 0><<<512, 256, 0, stream>>>(
      U(o_ow3h), nullptr, U(o_t2p), ob3, nullptr, nullptr, nullptr,
      nullptr, U(o_off3), 512);
  // D3: deform(t2, off3) -> h3
  deform_k<256, 0><<<16384, 256, 0, stream>>>(U(o_t2p), U(o_off3), U(o_h3));
  // G6: conv3 1x1 + BN3 + ReLU -> d_out (NCHW fp32)
  gemm_conv<1, 0, 2, 256, 0><<<1024, 256, 0, stream>>>(
      U(o_w3h), nullptr, U(o_h3), g3, b3, m3, v3, (float*)d_out, nullptr, 1024);
}